// Round 1
// baseline (2142.160 us; speedup 1.0000x reference)
//
#include <hip/hip_runtime.h>
#include <math.h>

// Problem constants
#define BB 32
#define LL 512
#define DD 512
#define NH 8
#define HD 64
// qkv row stride (3*D)
#define QKV_LD 1536

// ---------------- reductions ----------------
__device__ __forceinline__ float warp_sum(float v) {
    #pragma unroll
    for (int o = 32; o > 0; o >>= 1) v += __shfl_down(v, o);
    return v;
}
__device__ __forceinline__ float warp_max(float v) {
    #pragma unroll
    for (int o = 32; o > 0; o >>= 1) v = fmaxf(v, __shfl_down(v, o));
    return v;
}

// ---------------- LayerNorm: one block per row of 512 ----------------
__global__ void ln_kernel(const float* __restrict__ X, const float* __restrict__ g,
                          const float* __restrict__ b, float* __restrict__ Y) {
    __shared__ float red[8];
    const size_t base = (size_t)blockIdx.x * DD;
    const int t = threadIdx.x;
    float x0 = X[base + t], x1 = X[base + t + 256];
    float s = warp_sum(x0 + x1);
    float q = warp_sum(x0 * x0 + x1 * x1);
    if ((t & 63) == 0) { red[t >> 6] = s; red[4 + (t >> 6)] = q; }
    __syncthreads();
    float S = red[0] + red[1] + red[2] + red[3];
    float Q = red[4] + red[5] + red[6] + red[7];
    float mu  = S * (1.0f / 512.0f);
    float var = Q * (1.0f / 512.0f) - mu * mu;
    float r = rsqrtf(var + 1e-5f);
    Y[base + t]       = (x0 - mu) * r * g[t] + b[t];
    Y[base + t + 256] = (x1 - mu) * r * g[t + 256] + b[t + 256];
}

// ---------------- generic tiled fp32 GEMM: C = act(A@B + bias) (+res) ----------------
// 64x64 tile, BK=16, 256 threads, 4x4 per thread.
__device__ __forceinline__ float gelu_exact(float x) {
    return 0.5f * x * (1.0f + erff(x * 0.70710678118654752f));
}

template <int ACT, bool HAS_RES>
__global__ void gemm_kernel(const float* __restrict__ A, const float* __restrict__ Bw,
                            const float* __restrict__ bias, const float* __restrict__ res,
                            float* __restrict__ C, int M, int N, int K) {
    __shared__ float As[16][64];   // transposed: As[k][m]
    __shared__ float Bs[16][68];   // Bs[k][n], padded
    const int bm = blockIdx.y * 64, bn = blockIdx.x * 64;
    const int tid = threadIdx.x;
    const int tm = tid >> 4, tn = tid & 15;
    const int arow = tid >> 2, ac4 = (tid & 3) * 4;
    const int brow = tid >> 4, bc4 = (tid & 15) * 4;
    float acc[4][4] = {};
    for (int k0 = 0; k0 < K; k0 += 16) {
        float4 a  = *(const float4*)(A  + (size_t)(bm + arow) * K + k0 + ac4);
        float4 bv = *(const float4*)(Bw + (size_t)(k0 + brow) * N + bn + bc4);
        As[ac4 + 0][arow] = a.x; As[ac4 + 1][arow] = a.y;
        As[ac4 + 2][arow] = a.z; As[ac4 + 3][arow] = a.w;
        *(float4*)&Bs[brow][bc4] = bv;
        __syncthreads();
        #pragma unroll
        for (int k = 0; k < 16; ++k) {
            float4 av = *(const float4*)&As[k][tm * 4];
            float4 bb = *(const float4*)&Bs[k][tn * 4];
            const float* ar = (const float*)&av;
            const float* br = (const float*)&bb;
            #pragma unroll
            for (int i = 0; i < 4; ++i)
                #pragma unroll
                for (int j = 0; j < 4; ++j) acc[i][j] += ar[i] * br[j];
        }
        __syncthreads();
    }
    #pragma unroll
    for (int i = 0; i < 4; ++i) {
        const int row = bm + tm * 4 + i;
        const int col = bn + tn * 4;
        float4 outv;
        float* o = (float*)&outv;
        #pragma unroll
        for (int j = 0; j < 4; ++j) {
            float v = acc[i][j] + bias[col + j];
            if (ACT == 1) v = gelu_exact(v);
            if (HAS_RES) v += res[(size_t)row * N + col + j];
            o[j] = v;
        }
        *(float4*)(C + (size_t)row * N + col) = outv;
    }
}

// ---------------- bias matrix: Bias[b,h,q,k] = sum_f inter[b,q,k,f]*iw[f,h] ----------------
__global__ void biasmat_kernel(const float* __restrict__ inter, const float* __restrict__ iw,
                               float* __restrict__ Bias) {
    const int idx = blockIdx.x * 256 + threadIdx.x;  // 0 .. B*L*L-1
    float4 f = *(const float4*)(inter + (size_t)idx * 4);
    const int b = idx >> 18;
    const int q = (idx >> 9) & 511;
    const int k = idx & 511;
    #pragma unroll
    for (int h = 0; h < NH; ++h) {
        float v = f.x * iw[h] + f.y * iw[8 + h] + f.z * iw[16 + h] + f.w * iw[24 + h];
        Bias[(((size_t)b * NH + h) * LL + q) * LL + k] = v;
    }
}

// ---------------- scores: S[bh] += (Q[bh] @ K[bh]^T) / 8, in place over bias ----------------
__global__ void scores_kernel(const float* __restrict__ qkv, float* __restrict__ S) {
    __shared__ float Qs[64][68];
    __shared__ float Ks[64][68];
    const int bh = blockIdx.y, b = bh >> 3, h = bh & 7;
    const int qt = blockIdx.x >> 3, kt = blockIdx.x & 7;
    const float* Qb = qkv + (size_t)b * LL * QKV_LD + h * HD;
    const float* Kb = Qb + DD;
    float* Sb = S + (size_t)bh * (LL * LL);
    const int tid = threadIdx.x;
    const int row = tid >> 2, c = (tid & 3) * 16;
    const float* qp = Qb + (size_t)(qt * 64 + row) * QKV_LD + c;
    const float* kp = Kb + (size_t)(kt * 64 + row) * QKV_LD + c;
    #pragma unroll
    for (int j = 0; j < 16; j += 4) {
        *(float4*)&Qs[row][c + j] = *(const float4*)(qp + j);
        *(float4*)&Ks[row][c + j] = *(const float4*)(kp + j);
    }
    __syncthreads();
    const int tm = tid >> 4, tn = tid & 15;
    float acc[4][4] = {};
    #pragma unroll 4
    for (int k = 0; k < 64; k += 4) {
        float4 q4[4], k4[4];
        #pragma unroll
        for (int i = 0; i < 4; ++i) q4[i] = *(const float4*)&Qs[tm * 4 + i][k];
        #pragma unroll
        for (int j = 0; j < 4; ++j) k4[j] = *(const float4*)&Ks[tn * 4 + j][k];
        #pragma unroll
        for (int i = 0; i < 4; ++i)
            #pragma unroll
            for (int j = 0; j < 4; ++j)
                acc[i][j] += q4[i].x * k4[j].x + q4[i].y * k4[j].y +
                             q4[i].z * k4[j].z + q4[i].w * k4[j].w;
    }
    #pragma unroll
    for (int i = 0; i < 4; ++i) {
        float* sp = Sb + (size_t)(qt * 64 + tm * 4 + i) * LL + kt * 64 + tn * 4;
        float4 old = *(const float4*)sp;
        float4 outv;
        outv.x = acc[i][0] * 0.125f + old.x;
        outv.y = acc[i][1] * 0.125f + old.y;
        outv.z = acc[i][2] * 0.125f + old.z;
        outv.w = acc[i][3] * 0.125f + old.w;
        *(float4*)sp = outv;
    }
}

// ---------------- softmax over last dim (512), in place ----------------
__global__ void softmax_kernel(float* __restrict__ S) {
    __shared__ float redmax[4], redsum[4];
    float* row = S + (size_t)blockIdx.x * LL;
    const int t = threadIdx.x;
    float x0 = row[t], x1 = row[t + 256];
    float m = warp_max(fmaxf(x0, x1));
    if ((t & 63) == 0) redmax[t >> 6] = m;
    __syncthreads();
    float M = fmaxf(fmaxf(redmax[0], redmax[1]), fmaxf(redmax[2], redmax[3]));
    float e0 = __expf(x0 - M), e1 = __expf(x1 - M);
    float s = warp_sum(e0 + e1);
    if ((t & 63) == 0) redsum[t >> 6] = s;
    __syncthreads();
    float inv = 1.0f / (redsum[0] + redsum[1] + redsum[2] + redsum[3]);
    row[t] = e0 * inv;
    row[t + 256] = e1 * inv;
}

// ---------------- attn @ V: O[b, q, h*64+d] = sum_k P[bh,q,k] * V[bh,k,d] ----------------
__global__ void attnv_kernel(const float* __restrict__ P, const float* __restrict__ qkv,
                             float* __restrict__ O) {
    __shared__ float Ps[16][64];   // transposed [k][m]
    __shared__ float Vs[16][68];   // [k][n]
    const int bh = blockIdx.y, b = bh >> 3, h = bh & 7;
    const int qt = blockIdx.x;
    const float* Pb = P + (size_t)bh * (LL * LL);
    const float* Vb = qkv + (size_t)b * LL * QKV_LD + 2 * DD + h * HD;
    const int tid = threadIdx.x;
    const int tm = tid >> 4, tn = tid & 15;
    const int prow = tid >> 2, pc4 = (tid & 3) * 4;
    const int vrow = tid >> 4, vc4 = (tid & 15) * 4;
    float acc[4][4] = {};
    for (int k0 = 0; k0 < LL; k0 += 16) {
        float4 p = *(const float4*)(Pb + (size_t)(qt * 64 + prow) * LL + k0 + pc4);
        float4 v = *(const float4*)(Vb + (size_t)(k0 + vrow) * QKV_LD + vc4);
        Ps[pc4 + 0][prow] = p.x; Ps[pc4 + 1][prow] = p.y;
        Ps[pc4 + 2][prow] = p.z; Ps[pc4 + 3][prow] = p.w;
        *(float4*)&Vs[vrow][vc4] = v;
        __syncthreads();
        #pragma unroll
        for (int k = 0; k < 16; ++k) {
            float4 av = *(const float4*)&Ps[k][tm * 4];
            float4 bb = *(const float4*)&Vs[k][tn * 4];
            const float* ar = (const float*)&av;
            const float* br = (const float*)&bb;
            #pragma unroll
            for (int i = 0; i < 4; ++i)
                #pragma unroll
                for (int j = 0; j < 4; ++j) acc[i][j] += ar[i] * br[j];
        }
        __syncthreads();
    }
    #pragma unroll
    for (int i = 0; i < 4; ++i) {
        float4 outv;
        outv.x = acc[i][0]; outv.y = acc[i][1]; outv.z = acc[i][2]; outv.w = acc[i][3];
        *(float4*)(O + (size_t)(b * LL + qt * 64 + tm * 4 + i) * DD + h * HD + tn * 4) = outv;
    }
}

// ---------------- launch ----------------
extern "C" void kernel_launch(void* const* d_in, const int* in_sizes, int n_in,
                              void* d_out, int out_size, void* d_ws, size_t ws_size,
                              hipStream_t stream) {
    const float* x     = (const float*)d_in[0];
    const float* inter = (const float*)d_in[1];
    const float* qkv_w = (const float*)d_in[2];
    const float* qkv_b = (const float*)d_in[3];
    const float* out_w = (const float*)d_in[4];
    const float* out_b = (const float*)d_in[5];
    const float* n1g   = (const float*)d_in[6];
    const float* n1b   = (const float*)d_in[7];
    const float* n2g   = (const float*)d_in[8];
    const float* n2b   = (const float*)d_in[9];
    const float* iw    = (const float*)d_in[10];
    const float* fw1   = (const float*)d_in[11];
    const float* fb1   = (const float*)d_in[12];
    const float* fw2   = (const float*)d_in[13];
    const float* fb2   = (const float*)d_in[14];
    float* out = (float*)d_out;

    // workspace layout (bytes):
    //   h       @ 0          : 33,554,432   (B*L*D fp32; reused for h2)
    //   qkv     @ 33554432   : 100,663,296  (B*L*3D fp32)
    //   biasS   @ 134217728  : 268,435,456  (B*H*L*L fp32; bias -> scores -> softmax -> P; reused for ffn_mid)
    //   attnout @ 402653184  : 33,554,432
    //   x2      @ 436207616  : 33,554,432
    // total needed: 469,762,048 bytes
    if (ws_size < 469762048ull) return;  // signal: output stays zero -> clean fail
    char* ws = (char*)d_ws;
    float* h       = (float*)(ws);
    float* qkv     = (float*)(ws + 33554432ull);
    float* biasS   = (float*)(ws + 134217728ull);
    float* attnout = (float*)(ws + 402653184ull);
    float* x2      = (float*)(ws + 436207616ull);
    float* ffnmid  = biasS;  // reuse: attention is done by the time ffn1 runs

    const int M = BB * LL;  // 16384

    // 1. LN1: x -> h
    ln_kernel<<<M, 256, 0, stream>>>(x, n1g, n1b, h);
    // 2. qkv = h @ qkv_w + qkv_b    (16384 x 1536, K=512)
    gemm_kernel<0, false><<<dim3(1536 / 64, M / 64), 256, 0, stream>>>(
        h, qkv_w, qkv_b, nullptr, qkv, M, 1536, 512);
    // 3. bias matrix from inter
    biasmat_kernel<<<(BB * LL * LL) / 256, 256, 0, stream>>>(inter, iw, biasS);
    // 4. scores += QK^T / 8 (in place over bias)
    scores_kernel<<<dim3(64, BB * NH), 256, 0, stream>>>(qkv, biasS);
    // 5. softmax rows
    softmax_kernel<<<BB * NH * LL, 256, 0, stream>>>(biasS);
    // 6. O = P @ V  -> attnout (B,L,D)
    attnv_kernel<<<dim3(LL / 64, BB * NH), 256, 0, stream>>>(biasS, qkv, attnout);
    // 7. x2 = x + attnout @ out_w + out_b   (16384 x 512, K=512)
    gemm_kernel<0, true><<<dim3(512 / 64, M / 64), 256, 0, stream>>>(
        attnout, out_w, out_b, x, x2, M, 512, 512);
    // 8. LN2: x2 -> h (reuse)
    ln_kernel<<<M, 256, 0, stream>>>(x2, n2g, n2b, h);
    // 9. ffn_mid = gelu(h @ fw1 + fb1)   (16384 x 2048, K=512)
    gemm_kernel<1, false><<<dim3(2048 / 64, M / 64), 256, 0, stream>>>(
        h, fw1, fb1, nullptr, ffnmid, M, 2048, 512);
    // 10. out = x2 + ffn_mid @ fw2 + fb2  (16384 x 512, K=2048)
    gemm_kernel<0, true><<<dim3(512 / 64, M / 64), 256, 0, stream>>>(
        ffnmid, fw2, fb2, x2, out, M, 512, 2048);
}

// Round 2
// 947.482 us; speedup vs baseline: 2.2609x; 2.2609x over previous
//
#include <hip/hip_runtime.h>
#include <math.h>

#define BB 32
#define LL 512
#define DD 512
#define NH 8
#define HD 64
#define QKV_LD 1536

typedef __attribute__((ext_vector_type(8))) short bf16x8;
typedef __attribute__((ext_vector_type(4))) float f32x4;

__device__ __forceinline__ unsigned short f2bf(float x) {
    union { float f; unsigned u; } v; v.f = x;
    unsigned r = v.u + 0x7fffu + ((v.u >> 16) & 1u);  // RNE
    return (unsigned short)(r >> 16);
}

// ---------------- reductions ----------------
__device__ __forceinline__ float warp_sum(float v) {
    #pragma unroll
    for (int o = 32; o > 0; o >>= 1) v += __shfl_down(v, o);
    return v;
}
__device__ __forceinline__ float warp_max(float v) {
    #pragma unroll
    for (int o = 32; o > 0; o >>= 1) v = fmaxf(v, __shfl_down(v, o));
    return v;
}

// ---------------- LayerNorm: one block per row of 512 ----------------
template <int OUT_BF16>
__global__ void ln_kernel(const float* __restrict__ X, const float* __restrict__ g,
                          const float* __restrict__ b, void* __restrict__ Yv) {
    __shared__ float red[8];
    const size_t base = (size_t)blockIdx.x * DD;
    const int t = threadIdx.x;
    float x0 = X[base + t], x1 = X[base + t + 256];
    float s = warp_sum(x0 + x1);
    float q = warp_sum(x0 * x0 + x1 * x1);
    if ((t & 63) == 0) { red[t >> 6] = s; red[4 + (t >> 6)] = q; }
    __syncthreads();
    float S = red[0] + red[1] + red[2] + red[3];
    float Q = red[4] + red[5] + red[6] + red[7];
    float mu  = S * (1.0f / 512.0f);
    float var = Q * (1.0f / 512.0f) - mu * mu;
    float r = rsqrtf(var + 1e-5f);
    float y0 = (x0 - mu) * r * g[t] + b[t];
    float y1 = (x1 - mu) * r * g[t + 256] + b[t + 256];
    if (OUT_BF16) {
        unsigned short* Y = (unsigned short*)Yv;
        Y[base + t] = f2bf(y0);
        Y[base + t + 256] = f2bf(y1);
    } else {
        float* Y = (float*)Yv;
        Y[base + t] = y0;
        Y[base + t + 256] = y1;
    }
}

// ---------------- weight transpose + bf16 cast: W (K x N) -> WT (N x K) ----------------
__global__ void transpose_bf16(const float* __restrict__ W, unsigned short* __restrict__ WT,
                               int K, int N) {
    __shared__ float t[32][33];
    const int n0 = blockIdx.x * 32, k0 = blockIdx.y * 32;
    const int tx = threadIdx.x & 31, ty = threadIdx.x >> 5;  // 8 rows/pass
    #pragma unroll
    for (int r = 0; r < 32; r += 8)
        t[ty + r][tx] = W[(size_t)(k0 + ty + r) * N + n0 + tx];
    __syncthreads();
    #pragma unroll
    for (int r = 0; r < 32; r += 8)
        WT[(size_t)(n0 + ty + r) * K + k0 + tx] = f2bf(t[tx][ty + r]);
}

// ---------------- bf16 MFMA GEMM: C = act(A @ BT^T + bias) (+res) ----------------
// A: M x K bf16 row-major; BT: N x K bf16 row-major (i.e. B transposed).
// 128x128 tile, BK=64, 256 threads (4 waves, 2x2), 4x4 MFMA tiles per wave.
// LDS staged via global_load_lds(16B) with XOR-chunk swizzle (lane-linear dst).
template <int ACT, int RES, int OUTBF>
__global__ __launch_bounds__(256)
void gemm_mfma(const unsigned short* __restrict__ A, const unsigned short* __restrict__ BT,
               const float* __restrict__ bias, const float* __restrict__ res,
               void* __restrict__ Cv, int M, int N, int K) {
    __shared__ unsigned short As[128 * 64];
    __shared__ unsigned short Bs[128 * 64];
    const int tid = threadIdx.x;
    const int wave = tid >> 6, lane = tid & 63;
    const int wm = (wave >> 1) * 64, wn = (wave & 1) * 64;
    const int bm = blockIdx.y * 128, bn = blockIdx.x * 128;

    f32x4 acc[4][4] = {};

    for (int k0 = 0; k0 < K; k0 += 64) {
        __syncthreads();  // protect LDS before overwrite
        #pragma unroll
        for (int it = 0; it < 4; ++it) {
            const int s = it * 256 + tid;            // 16B-chunk slot: 128 rows x 8 chunks
            const int row = s >> 3, pch = s & 7;
            const int lch = pch ^ (row & 7);         // XOR swizzle
            const unsigned short* ga = A + (size_t)(bm + row) * K + k0 + lch * 8;
            __builtin_amdgcn_global_load_lds(
                (const __attribute__((address_space(1))) void*)ga,
                (__attribute__((address_space(3))) void*)(As + s * 8), 16, 0, 0);
            const unsigned short* gb = BT + (size_t)(bn + row) * K + k0 + lch * 8;
            __builtin_amdgcn_global_load_lds(
                (const __attribute__((address_space(1))) void*)gb,
                (__attribute__((address_space(3))) void*)(Bs + s * 8), 16, 0, 0);
        }
        __syncthreads();  // drains vmcnt before barrier (compiler-inserted)
        #pragma unroll
        for (int ks = 0; ks < 2; ++ks) {
            bf16x8 af[4], bfr[4];
            #pragma unroll
            for (int i = 0; i < 4; ++i) {
                const int row = wm + i * 16 + (lane & 15);
                const int pch = (ks * 4 + (lane >> 4)) ^ (row & 7);
                af[i] = *(const bf16x8*)(As + row * 64 + pch * 8);
            }
            #pragma unroll
            for (int j = 0; j < 4; ++j) {
                const int row = wn + j * 16 + (lane & 15);
                const int pch = (ks * 4 + (lane >> 4)) ^ (row & 7);
                bfr[j] = *(const bf16x8*)(Bs + row * 64 + pch * 8);
            }
            #pragma unroll
            for (int i = 0; i < 4; ++i)
                #pragma unroll
                for (int j = 0; j < 4; ++j)
                    acc[i][j] = __builtin_amdgcn_mfma_f32_16x16x32_bf16(
                        af[i], bfr[j], acc[i][j], 0, 0, 0);
        }
    }

    // epilogue: C/D layout col=lane&15, row=(lane>>4)*4+reg  [verified m89/m91]
    const int cl = lane & 15, rq = (lane >> 4) * 4;
    #pragma unroll
    for (int j = 0; j < 4; ++j) {
        const int col = bn + wn + j * 16 + cl;
        const float bv = bias[col];
        #pragma unroll
        for (int i = 0; i < 4; ++i) {
            const int r0 = bm + wm + i * 16 + rq;
            #pragma unroll
            for (int r = 0; r < 4; ++r) {
                float v = acc[i][j][r] + bv;
                if (ACT == 1) v = 0.5f * v * (1.0f + erff(v * 0.70710678118654752f));
                if (RES) v += res[(size_t)(r0 + r) * N + col];
                if (OUTBF) ((unsigned short*)Cv)[(size_t)(r0 + r) * N + col] = f2bf(v);
                else       ((float*)Cv)[(size_t)(r0 + r) * N + col] = v;
            }
        }
    }
}

// ---------------- bias matrix: Bias[b,h,q,k] = sum_f inter[b,q,k,f]*iw[f,h] ----------------
__global__ void biasmat_kernel(const float* __restrict__ inter, const float* __restrict__ iw,
                               float* __restrict__ Bias) {
    const int idx = blockIdx.x * 256 + threadIdx.x;
    float4 f = *(const float4*)(inter + (size_t)idx * 4);
    const int b = idx >> 18;
    const int q = (idx >> 9) & 511;
    const int k = idx & 511;
    #pragma unroll
    for (int h = 0; h < NH; ++h) {
        float v = f.x * iw[h] + f.y * iw[8 + h] + f.z * iw[16 + h] + f.w * iw[24 + h];
        Bias[(((size_t)b * NH + h) * LL + q) * LL + k] = v;
    }
}

// ---------------- scores: S[bh] += (Q[bh] @ K[bh]^T) / 8, in place over bias ----------------
__global__ void scores_kernel(const float* __restrict__ qkv, float* __restrict__ S) {
    __shared__ float Qs[64][68];
    __shared__ float Ks[64][68];
    const int bh = blockIdx.y, b = bh >> 3, h = bh & 7;
    const int qt = blockIdx.x >> 3, kt = blockIdx.x & 7;
    const float* Qb = qkv + (size_t)b * LL * QKV_LD + h * HD;
    const float* Kb = Qb + DD;
    float* Sb = S + (size_t)bh * (LL * LL);
    const int tid = threadIdx.x;
    const int row = tid >> 2, c = (tid & 3) * 16;
    const float* qp = Qb + (size_t)(qt * 64 + row) * QKV_LD + c;
    const float* kp = Kb + (size_t)(kt * 64 + row) * QKV_LD + c;
    #pragma unroll
    for (int j = 0; j < 16; j += 4) {
        *(float4*)&Qs[row][c + j] = *(const float4*)(qp + j);
        *(float4*)&Ks[row][c + j] = *(const float4*)(kp + j);
    }
    __syncthreads();
    const int tm = tid >> 4, tn = tid & 15;
    float acc[4][4] = {};
    #pragma unroll 4
    for (int k = 0; k < 64; k += 4) {
        float4 q4[4], k4[4];
        #pragma unroll
        for (int i = 0; i < 4; ++i) q4[i] = *(const float4*)&Qs[tm * 4 + i][k];
        #pragma unroll
        for (int j = 0; j < 4; ++j) k4[j] = *(const float4*)&Ks[tn * 4 + j][k];
        #pragma unroll
        for (int i = 0; i < 4; ++i)
            #pragma unroll
            for (int j = 0; j < 4; ++j)
                acc[i][j] += q4[i].x * k4[j].x + q4[i].y * k4[j].y +
                             q4[i].z * k4[j].z + q4[i].w * k4[j].w;
    }
    #pragma unroll
    for (int i = 0; i < 4; ++i) {
        float* sp = Sb + (size_t)(qt * 64 + tm * 4 + i) * LL + kt * 64 + tn * 4;
        float4 old = *(const float4*)sp;
        float4 outv;
        outv.x = acc[i][0] * 0.125f + old.x;
        outv.y = acc[i][1] * 0.125f + old.y;
        outv.z = acc[i][2] * 0.125f + old.z;
        outv.w = acc[i][3] * 0.125f + old.w;
        *(float4*)sp = outv;
    }
}

// ---------------- softmax over last dim (512), in place ----------------
__global__ void softmax_kernel(float* __restrict__ S) {
    __shared__ float redmax[4], redsum[4];
    float* row = S + (size_t)blockIdx.x * LL;
    const int t = threadIdx.x;
    float x0 = row[t], x1 = row[t + 256];
    float m = warp_max(fmaxf(x0, x1));
    if ((t & 63) == 0) redmax[t >> 6] = m;
    __syncthreads();
    float M = fmaxf(fmaxf(redmax[0], redmax[1]), fmaxf(redmax[2], redmax[3]));
    float e0 = __expf(x0 - M), e1 = __expf(x1 - M);
    float s = warp_sum(e0 + e1);
    if ((t & 63) == 0) redsum[t >> 6] = s;
    __syncthreads();
    float inv = 1.0f / (redsum[0] + redsum[1] + redsum[2] + redsum[3]);
    row[t] = e0 * inv;
    row[t + 256] = e1 * inv;
}

// ---------------- attn @ V -> bf16 A-matrix for out-proj ----------------
__global__ void attnv_kernel(const float* __restrict__ P, const float* __restrict__ qkv,
                             unsigned short* __restrict__ O) {
    __shared__ float Ps[16][64];
    __shared__ float Vs[16][68];
    const int bh = blockIdx.y, b = bh >> 3, h = bh & 7;
    const int qt = blockIdx.x;
    const float* Pb = P + (size_t)bh * (LL * LL);
    const float* Vb = qkv + (size_t)b * LL * QKV_LD + 2 * DD + h * HD;
    const int tid = threadIdx.x;
    const int tm = tid >> 4, tn = tid & 15;
    const int prow = tid >> 2, pc4 = (tid & 3) * 4;
    const int vrow = tid >> 4, vc4 = (tid & 15) * 4;
    float acc[4][4] = {};
    for (int k0 = 0; k0 < LL; k0 += 16) {
        float4 p = *(const float4*)(Pb + (size_t)(qt * 64 + prow) * LL + k0 + pc4);
        float4 v = *(const float4*)(Vb + (size_t)(k0 + vrow) * QKV_LD + vc4);
        Ps[pc4 + 0][prow] = p.x; Ps[pc4 + 1][prow] = p.y;
        Ps[pc4 + 2][prow] = p.z; Ps[pc4 + 3][prow] = p.w;
        *(float4*)&Vs[vrow][vc4] = v;
        __syncthreads();
        #pragma unroll
        for (int k = 0; k < 16; ++k) {
            float4 av = *(const float4*)&Ps[k][tm * 4];
            float4 bb = *(const float4*)&Vs[k][tn * 4];
            const float* ar = (const float*)&av;
            const float* br = (const float*)&bb;
            #pragma unroll
            for (int i = 0; i < 4; ++i)
                #pragma unroll
                for (int j = 0; j < 4; ++j) acc[i][j] += ar[i] * br[j];
        }
        __syncthreads();
    }
    #pragma unroll
    for (int i = 0; i < 4; ++i) {
        ushort4 outv;
        outv.x = f2bf(acc[i][0]); outv.y = f2bf(acc[i][1]);
        outv.z = f2bf(acc[i][2]); outv.w = f2bf(acc[i][3]);
        *(ushort4*)(O + (size_t)(b * LL + qt * 64 + tm * 4 + i) * DD + h * HD + tn * 4) = outv;
    }
}

// ---------------- launch ----------------
extern "C" void kernel_launch(void* const* d_in, const int* in_sizes, int n_in,
                              void* d_out, int out_size, void* d_ws, size_t ws_size,
                              hipStream_t stream) {
    const float* x     = (const float*)d_in[0];
    const float* inter = (const float*)d_in[1];
    const float* qkv_w = (const float*)d_in[2];
    const float* qkv_b = (const float*)d_in[3];
    const float* out_w = (const float*)d_in[4];
    const float* out_b = (const float*)d_in[5];
    const float* n1g   = (const float*)d_in[6];
    const float* n1b   = (const float*)d_in[7];
    const float* n2g   = (const float*)d_in[8];
    const float* n2b   = (const float*)d_in[9];
    const float* iw    = (const float*)d_in[10];
    const float* fw1   = (const float*)d_in[11];
    const float* fb1   = (const float*)d_in[12];
    const float* fw2   = (const float*)d_in[13];
    const float* fb2   = (const float*)d_in[14];
    float* out = (float*)d_out;

    // workspace layout (bytes):
    //   qkv     @ 0           : 100,663,296  (B*L*3D fp32)
    //   biasS   @ 100663296   : 268,435,456  (B*H*L*L fp32; also reused as ffnmid bf16)
    //   x2      @ 369098752   :  33,554,432  (fp32)
    //   h_bf16  @ 402653184   :  16,777,216  (B*L*D bf16; LN1/LN2 out)
    //   attnout @ 419430400   :  16,777,216  (bf16)
    //   qkv_wT  @ 436207616   :   1,572,864
    //   out_wT  @ 437780480   :     524,288
    //   fw1T    @ 438304768   :   2,097,152
    //   fw2T    @ 440401920   :   2,097,152
    // total: 442,499,072
    if (ws_size < 442499072ull) return;
    char* ws = (char*)d_ws;
    float*          qkv     = (float*)(ws);
    float*          biasS   = (float*)(ws + 100663296ull);
    float*          x2      = (float*)(ws + 369098752ull);
    unsigned short* h_bf    = (unsigned short*)(ws + 402653184ull);
    unsigned short* attnout = (unsigned short*)(ws + 419430400ull);
    unsigned short* qkv_wT  = (unsigned short*)(ws + 436207616ull);
    unsigned short* out_wT  = (unsigned short*)(ws + 437780480ull);
    unsigned short* fw1T    = (unsigned short*)(ws + 438304768ull);
    unsigned short* fw2T    = (unsigned short*)(ws + 440401920ull);
    unsigned short* ffnmid  = (unsigned short*)biasS;  // reuse after attention

    const int M = BB * LL;  // 16384

    // 0. weight transposes -> bf16 B^T
    transpose_bf16<<<dim3(1536 / 32, 512 / 32), 256, 0, stream>>>(qkv_w, qkv_wT, 512, 1536);
    transpose_bf16<<<dim3(512 / 32, 512 / 32), 256, 0, stream>>>(out_w, out_wT, 512, 512);
    transpose_bf16<<<dim3(2048 / 32, 512 / 32), 256, 0, stream>>>(fw1, fw1T, 512, 2048);
    transpose_bf16<<<dim3(512 / 32, 2048 / 32), 256, 0, stream>>>(fw2, fw2T, 2048, 512);
    // 1. LN1: x -> h_bf16
    ln_kernel<1><<<M, 256, 0, stream>>>(x, n1g, n1b, h_bf);
    // 2. qkv = h @ qkv_w + qkv_b  (fp32 out for fp32 attention)
    gemm_mfma<0, 0, 0><<<dim3(1536 / 128, M / 128), 256, 0, stream>>>(
        h_bf, qkv_wT, qkv_b, nullptr, qkv, M, 1536, 512);
    // 3. bias matrix from inter
    biasmat_kernel<<<(BB * LL * LL) / 256, 256, 0, stream>>>(inter, iw, biasS);
    // 4. scores += QK^T / 8
    scores_kernel<<<dim3(64, BB * NH), 256, 0, stream>>>(qkv, biasS);
    // 5. softmax
    softmax_kernel<<<BB * NH * LL, 256, 0, stream>>>(biasS);
    // 6. O = P @ V -> attnout (bf16)
    attnv_kernel<<<dim3(LL / 64, BB * NH), 256, 0, stream>>>(biasS, qkv, attnout);
    // 7. x2 = x + attnout @ out_w + out_b
    gemm_mfma<0, 1, 0><<<dim3(512 / 128, M / 128), 256, 0, stream>>>(
        attnout, out_wT, out_b, x, x2, M, 512, 512);
    // 8. LN2: x2 -> h_bf16
    ln_kernel<1><<<M, 256, 0, stream>>>(x2, n2g, n2b, h_bf);
    // 9. ffnmid = gelu(h2 @ fw1 + fb1) -> bf16
    gemm_mfma<1, 0, 1><<<dim3(2048 / 128, M / 128), 256, 0, stream>>>(
        h_bf, fw1T, fb1, nullptr, ffnmid, M, 2048, 512);
    // 10. out = x2 + ffnmid @ fw2 + fb2
    gemm_mfma<0, 1, 0><<<dim3(512 / 128, M / 128), 256, 0, stream>>>(
        ffnmid, fw2T, fb2, x2, out, M, 512, 2048);
}

// Round 3
// 731.872 us; speedup vs baseline: 2.9270x; 1.2946x over previous
//
#include <hip/hip_runtime.h>
#include <math.h>

#define BB 32
#define LL 512
#define DD 512
#define NH 8
#define HD 64

typedef __attribute__((ext_vector_type(8))) short bf16x8;
typedef __attribute__((ext_vector_type(4))) float f32x4;

__device__ __forceinline__ unsigned short f2bf(float x) {
    union { float f; unsigned u; } v; v.f = x;
    unsigned r = v.u + 0x7fffu + ((v.u >> 16) & 1u);  // RNE
    return (unsigned short)(r >> 16);
}

// ---------------- reductions ----------------
__device__ __forceinline__ float warp_sum(float v) {
    #pragma unroll
    for (int o = 32; o > 0; o >>= 1) v += __shfl_down(v, o);
    return v;
}

// ---------------- LayerNorm: one block per row of 512, bf16 out ----------------
__global__ void ln_kernel(const float* __restrict__ X, const float* __restrict__ g,
                          const float* __restrict__ b, unsigned short* __restrict__ Y) {
    __shared__ float red[8];
    const size_t base = (size_t)blockIdx.x * DD;
    const int t = threadIdx.x;
    float x0 = X[base + t], x1 = X[base + t + 256];
    float s = warp_sum(x0 + x1);
    float q = warp_sum(x0 * x0 + x1 * x1);
    if ((t & 63) == 0) { red[t >> 6] = s; red[4 + (t >> 6)] = q; }
    __syncthreads();
    float S = red[0] + red[1] + red[2] + red[3];
    float Q = red[4] + red[5] + red[6] + red[7];
    float mu  = S * (1.0f / 512.0f);
    float var = Q * (1.0f / 512.0f) - mu * mu;
    float r = rsqrtf(var + 1e-5f);
    Y[base + t]       = f2bf((x0 - mu) * r * g[t] + b[t]);
    Y[base + t + 256] = f2bf((x1 - mu) * r * g[t + 256] + b[t + 256]);
}

// ---------------- weight transpose + bf16 cast: W (K x N) -> WT (N x K) ----------------
__global__ void transpose_bf16(const float* __restrict__ W, unsigned short* __restrict__ WT,
                               int K, int N) {
    __shared__ float t[32][33];
    const int n0 = blockIdx.x * 32, k0 = blockIdx.y * 32;
    const int tx = threadIdx.x & 31, ty = threadIdx.x >> 5;
    #pragma unroll
    for (int r = 0; r < 32; r += 8)
        t[ty + r][tx] = W[(size_t)(k0 + ty + r) * N + n0 + tx];
    __syncthreads();
    #pragma unroll
    for (int r = 0; r < 32; r += 8)
        WT[(size_t)(n0 + ty + r) * K + k0 + tx] = f2bf(t[tx][ty + r]);
}

// ---------------- bf16 MFMA GEMM ----------------
// A: M x K bf16 row-major; BT: N x K bf16 row-major. 128x128 tile, BK=64.
// OM: 0 = f32 out, 1 = bf16 out, 2 = qkv split (Q,K -> Cv stride 1024; V -> vTout transposed)
template <int ACT, int RES, int OM>
__global__ __launch_bounds__(256)
void gemm_mfma(const unsigned short* __restrict__ A, const unsigned short* __restrict__ BT,
               const float* __restrict__ bias, const float* __restrict__ res,
               void* __restrict__ Cv, unsigned short* __restrict__ vTout,
               int M, int N, int K) {
    __shared__ unsigned short As[128 * 64];
    __shared__ unsigned short Bs[128 * 64];
    const int tid = threadIdx.x;
    const int wave = tid >> 6, lane = tid & 63;
    const int wm = (wave >> 1) * 64, wn = (wave & 1) * 64;
    const int bm = blockIdx.y * 128, bn = blockIdx.x * 128;

    f32x4 acc[4][4] = {};

    for (int k0 = 0; k0 < K; k0 += 64) {
        __syncthreads();
        #pragma unroll
        for (int it = 0; it < 4; ++it) {
            const int s = it * 256 + tid;
            const int row = s >> 3, pch = s & 7;
            const int lch = pch ^ (row & 7);
            const unsigned short* ga = A + (size_t)(bm + row) * K + k0 + lch * 8;
            __builtin_amdgcn_global_load_lds(
                (const __attribute__((address_space(1))) void*)ga,
                (__attribute__((address_space(3))) void*)(As + s * 8), 16, 0, 0);
            const unsigned short* gb = BT + (size_t)(bn + row) * K + k0 + lch * 8;
            __builtin_amdgcn_global_load_lds(
                (const __attribute__((address_space(1))) void*)gb,
                (__attribute__((address_space(3))) void*)(Bs + s * 8), 16, 0, 0);
        }
        __syncthreads();
        #pragma unroll
        for (int ks = 0; ks < 2; ++ks) {
            bf16x8 af[4], bfr[4];
            #pragma unroll
            for (int i = 0; i < 4; ++i) {
                const int row = wm + i * 16 + (lane & 15);
                const int pch = (ks * 4 + (lane >> 4)) ^ (row & 7);
                af[i] = *(const bf16x8*)(As + row * 64 + pch * 8);
            }
            #pragma unroll
            for (int j = 0; j < 4; ++j) {
                const int row = wn + j * 16 + (lane & 15);
                const int pch = (ks * 4 + (lane >> 4)) ^ (row & 7);
                bfr[j] = *(const bf16x8*)(Bs + row * 64 + pch * 8);
            }
            #pragma unroll
            for (int i = 0; i < 4; ++i)
                #pragma unroll
                for (int j = 0; j < 4; ++j)
                    acc[i][j] = __builtin_amdgcn_mfma_f32_16x16x32_bf16(
                        af[i], bfr[j], acc[i][j], 0, 0, 0);
        }
    }

    const int cl = lane & 15, rq = (lane >> 4) * 4;
    #pragma unroll
    for (int j = 0; j < 4; ++j) {
        const int col = bn + wn + j * 16 + cl;
        const float bv = bias[col];
        #pragma unroll
        for (int i = 0; i < 4; ++i) {
            const int r0 = bm + wm + i * 16 + rq;
            #pragma unroll
            for (int r = 0; r < 4; ++r) {
                float v = acc[i][j][r] + bv;
                if (ACT == 1) v = 0.5f * v * (1.0f + erff(v * 0.70710678118654752f));
                if (RES) v += res[(size_t)(r0 + r) * N + col];
                if (OM == 0) {
                    ((float*)Cv)[(size_t)(r0 + r) * N + col] = v;
                } else if (OM == 1) {
                    ((unsigned short*)Cv)[(size_t)(r0 + r) * N + col] = f2bf(v);
                } else {
                    const int row = r0 + r;
                    if (col < 1024) {
                        ((unsigned short*)Cv)[(size_t)row * 1024 + col] = f2bf(v);
                    } else {
                        const int hh = (col - 1024) >> 6, dd = (col - 1024) & 63;
                        vTout[(size_t)((((row >> 9) * NH + hh) << 6) + dd) * 512 + (row & 511)] = f2bf(v);
                    }
                }
            }
        }
    }
}

// ---------------- fused flash attention ----------------
// grid: (h=8, qtile=8, b=32), 256 threads = 4 waves; wave owns 16 q rows.
// qk: [B*512][1024] bf16  (cols 0..511 = Q(h*64+d), 512..1023 = K(h*64+d))
// vT: [B*NH][64][512] bf16  (V transposed: [d][kpos])
// O : [B*512][512] bf16
__global__ __launch_bounds__(256)
void flash_kernel(const unsigned short* __restrict__ qk,
                  const unsigned short* __restrict__ vT,
                  const float* __restrict__ inter,
                  const float* __restrict__ iw,
                  unsigned short* __restrict__ O) {
    __shared__ unsigned short plds[4][16 * 72];  // per-wave P tile, stride 72 (2-way free)
    const int h = blockIdx.x, qt = blockIdx.y, b = blockIdx.z;
    const int tid = threadIdx.x, wave = tid >> 6, lane = tid & 63;
    const int lo = lane & 15, hi = lane >> 4;
    const int qA  = qt * 64 + wave * 16 + lo;       // A-frag row (q)
    const int qC0 = qt * 64 + wave * 16 + hi * 4;   // C-layout row base (+reg)

    const float iw0 = iw[h], iw1 = iw[8 + h], iw2 = iw[16 + h], iw3 = iw[24 + h];

    // Q fragments (fixed for whole block)
    const unsigned short* qp = qk + ((size_t)(b * 512 + qA)) * 1024 + h * 64 + hi * 8;
    const bf16x8 qf0 = *(const bf16x8*)(qp);
    const bf16x8 qf1 = *(const bf16x8*)(qp + 32);

    f32x4 o[4] = {};
    float m[4] = {-1e30f, -1e30f, -1e30f, -1e30f};
    float lsum[4] = {};

    const float* interb = inter + (size_t)b * 512 * 512 * 4;
    const unsigned short* vbase = vT + ((size_t)(b * NH + h)) * 64 * 512;
    unsigned short* pw = &plds[wave][0];

    for (int kt = 0; kt < 8; ++kt) {
        const int kb = kt * 64;
        // ---- S = Q K^T ----
        f32x4 s[4] = {};
        const unsigned short* kp = qk + ((size_t)(b * 512 + kb)) * 1024 + 512 + h * 64 + hi * 8;
        #pragma unroll
        for (int kk = 0; kk < 2; ++kk) {
            const bf16x8 qf = kk ? qf1 : qf0;
            #pragma unroll
            for (int j = 0; j < 4; ++j) {
                bf16x8 kf = *(const bf16x8*)(kp + (size_t)(j * 16 + lo) * 1024 + kk * 32);
                s[j] = __builtin_amdgcn_mfma_f32_16x16x32_bf16(qf, kf, s[j], 0, 0, 0);
            }
        }
        // ---- bias + scale ----
        float sv[4][4];
        #pragma unroll
        for (int j = 0; j < 4; ++j) {
            const int kpos = kb + j * 16 + lo;
            #pragma unroll
            for (int r = 0; r < 4; ++r) {
                const float4 f = *(const float4*)(interb + ((size_t)(qC0 + r) * 512 + kpos) * 4);
                sv[j][r] = s[j][r] * 0.125f + f.x * iw0 + f.y * iw1 + f.z * iw2 + f.w * iw3;
            }
        }
        // ---- online softmax ----
        float alpha[4];
        #pragma unroll
        for (int r = 0; r < 4; ++r) {
            float t = fmaxf(fmaxf(sv[0][r], sv[1][r]), fmaxf(sv[2][r], sv[3][r]));
            #pragma unroll
            for (int off = 1; off < 16; off <<= 1) t = fmaxf(t, __shfl_xor(t, off));
            const float mn = fmaxf(m[r], t);
            alpha[r] = __expf(m[r] - mn);
            m[r] = mn;
        }
        float p[4][4];
        #pragma unroll
        for (int j = 0; j < 4; ++j)
            #pragma unroll
            for (int r = 0; r < 4; ++r)
                p[j][r] = __expf(sv[j][r] - m[r]);
        #pragma unroll
        for (int r = 0; r < 4; ++r) {
            float t = p[0][r] + p[1][r] + p[2][r] + p[3][r];
            #pragma unroll
            for (int off = 1; off < 16; off <<= 1) t += __shfl_xor(t, off);
            lsum[r] = lsum[r] * alpha[r] + t;
        }
        #pragma unroll
        for (int j2 = 0; j2 < 4; ++j2) {
            o[j2][0] *= alpha[0]; o[j2][1] *= alpha[1];
            o[j2][2] *= alpha[2]; o[j2][3] *= alpha[3];
        }
        // ---- P: C-layout -> LDS -> A-layout (wave-private, no barrier) ----
        #pragma unroll
        for (int j = 0; j < 4; ++j)
            #pragma unroll
            for (int r = 0; r < 4; ++r)
                pw[(hi * 4 + r) * 72 + j * 16 + lo] = f2bf(p[j][r]);
        // ---- O += P V ----
        #pragma unroll
        for (int kk = 0; kk < 2; ++kk) {
            const bf16x8 pf = *(const bf16x8*)(pw + lo * 72 + kk * 32 + hi * 8);
            #pragma unroll
            for (int j2 = 0; j2 < 4; ++j2) {
                bf16x8 vf = *(const bf16x8*)(vbase + (size_t)(j2 * 16 + lo) * 512 + kb + kk * 32 + hi * 8);
                o[j2] = __builtin_amdgcn_mfma_f32_16x16x32_bf16(pf, vf, o[j2], 0, 0, 0);
            }
        }
    }
    // ---- epilogue ----
    float inv[4];
    #pragma unroll
    for (int r = 0; r < 4; ++r) inv[r] = 1.0f / lsum[r];
    #pragma unroll
    for (int j2 = 0; j2 < 4; ++j2)
        #pragma unroll
        for (int r = 0; r < 4; ++r)
            O[(size_t)(b * 512 + qC0 + r) * 512 + h * 64 + j2 * 16 + lo] = f2bf(o[j2][r] * inv[r]);
}

// ---------------- launch ----------------
extern "C" void kernel_launch(void* const* d_in, const int* in_sizes, int n_in,
                              void* d_out, int out_size, void* d_ws, size_t ws_size,
                              hipStream_t stream) {
    const float* x     = (const float*)d_in[0];
    const float* inter = (const float*)d_in[1];
    const float* qkv_w = (const float*)d_in[2];
    const float* qkv_b = (const float*)d_in[3];
    const float* out_w = (const float*)d_in[4];
    const float* out_b = (const float*)d_in[5];
    const float* n1g   = (const float*)d_in[6];
    const float* n1b   = (const float*)d_in[7];
    const float* n2g   = (const float*)d_in[8];
    const float* n2b   = (const float*)d_in[9];
    const float* iw    = (const float*)d_in[10];
    const float* fw1   = (const float*)d_in[11];
    const float* fb1   = (const float*)d_in[12];
    const float* fw2   = (const float*)d_in[13];
    const float* fb2   = (const float*)d_in[14];
    float* out = (float*)d_out;

    // workspace layout (bytes):
    //   qk_bf   @ 0           : 33,554,432   (B*L x 1024 bf16: Q,K)
    //   vT      @ 33554432    : 16,777,216   (B*NH x 64 x 512 bf16)
    //   attnout @ 50331648    : 16,777,216   (bf16)
    //   x2      @ 67108864    : 33,554,432   (fp32)
    //   h_bf    @ 100663296   : 16,777,216   (bf16, LN out)
    //   ffnmid  @ 117440512   : 67,108,864   (16384 x 2048 bf16)
    //   qkv_wT  @ 184549376   : 1,572,864
    //   out_wT  @ 186122240   : 524,288
    //   fw1T    @ 186646528   : 2,097,152
    //   fw2T    @ 188743680   : 2,097,152
    // total: 190,840,832
    if (ws_size < 190840832ull) return;
    char* ws = (char*)d_ws;
    unsigned short* qk_bf   = (unsigned short*)(ws);
    unsigned short* vT      = (unsigned short*)(ws + 33554432ull);
    unsigned short* attnout = (unsigned short*)(ws + 50331648ull);
    float*          x2      = (float*)(ws + 67108864ull);
    unsigned short* h_bf    = (unsigned short*)(ws + 100663296ull);
    unsigned short* ffnmid  = (unsigned short*)(ws + 117440512ull);
    unsigned short* qkv_wT  = (unsigned short*)(ws + 184549376ull);
    unsigned short* out_wT  = (unsigned short*)(ws + 186122240ull);
    unsigned short* fw1T    = (unsigned short*)(ws + 186646528ull);
    unsigned short* fw2T    = (unsigned short*)(ws + 188743680ull);

    const int M = BB * LL;  // 16384

    // 0. weight transposes -> bf16 B^T
    transpose_bf16<<<dim3(1536 / 32, 512 / 32), 256, 0, stream>>>(qkv_w, qkv_wT, 512, 1536);
    transpose_bf16<<<dim3(512 / 32, 512 / 32), 256, 0, stream>>>(out_w, out_wT, 512, 512);
    transpose_bf16<<<dim3(2048 / 32, 512 / 32), 256, 0, stream>>>(fw1, fw1T, 512, 2048);
    transpose_bf16<<<dim3(512 / 32, 2048 / 32), 256, 0, stream>>>(fw2, fw2T, 2048, 512);
    // 1. LN1: x -> h_bf
    ln_kernel<<<M, 256, 0, stream>>>(x, n1g, n1b, h_bf);
    // 2. qkv GEMM -> qk_bf (Q,K) + vT (V transposed)
    gemm_mfma<0, 0, 2><<<dim3(1536 / 128, M / 128), 256, 0, stream>>>(
        h_bf, qkv_wT, qkv_b, nullptr, qk_bf, vT, M, 1536, 512);
    // 3. fused flash attention (bias from inter, online softmax) -> attnout
    flash_kernel<<<dim3(NH, LL / 64, BB), 256, 0, stream>>>(qk_bf, vT, inter, iw, attnout);
    // 4. x2 = x + attnout @ out_w + out_b
    gemm_mfma<0, 1, 0><<<dim3(512 / 128, M / 128), 256, 0, stream>>>(
        attnout, out_wT, out_b, x, x2, nullptr, M, 512, 512);
    // 5. LN2: x2 -> h_bf
    ln_kernel<<<M, 256, 0, stream>>>(x2, n2g, n2b, h_bf);
    // 6. ffnmid = gelu(h2 @ fw1 + fb1) -> bf16
    gemm_mfma<1, 0, 1><<<dim3(2048 / 128, M / 128), 256, 0, stream>>>(
        h_bf, fw1T, fb1, nullptr, ffnmid, nullptr, M, 2048, 512);
    // 7. out = x2 + ffnmid @ fw2 + fb2
    gemm_mfma<0, 1, 0><<<dim3(512 / 128, M / 128), 256, 0, stream>>>(
        ffnmid, fw2T, fb2, x2, out, nullptr, M, 512, 2048);
}

// Round 4
// 720.033 us; speedup vs baseline: 2.9751x; 1.0164x over previous
//
#include <hip/hip_runtime.h>
#include <math.h>

#define BB 32
#define LL 512
#define DD 512
#define NH 8
#define HD 64

typedef __attribute__((ext_vector_type(8))) short bf16x8;
typedef __attribute__((ext_vector_type(4))) float f32x4;

__device__ __forceinline__ unsigned short f2bf(float x) {
    union { float f; unsigned u; } v; v.f = x;
    unsigned r = v.u + 0x7fffu + ((v.u >> 16) & 1u);  // RNE
    return (unsigned short)(r >> 16);
}

// ---------------- reductions ----------------
__device__ __forceinline__ float warp_sum(float v) {
    #pragma unroll
    for (int o = 32; o > 0; o >>= 1) v += __shfl_down(v, o);
    return v;
}

// ---------------- LayerNorm: one block per row of 512, bf16 out ----------------
__global__ void ln_kernel(const float* __restrict__ X, const float* __restrict__ g,
                          const float* __restrict__ b, unsigned short* __restrict__ Y) {
    __shared__ float red[8];
    const size_t base = (size_t)blockIdx.x * DD;
    const int t = threadIdx.x;
    float x0 = X[base + t], x1 = X[base + t + 256];
    float s = warp_sum(x0 + x1);
    float q = warp_sum(x0 * x0 + x1 * x1);
    if ((t & 63) == 0) { red[t >> 6] = s; red[4 + (t >> 6)] = q; }
    __syncthreads();
    float S = red[0] + red[1] + red[2] + red[3];
    float Q = red[4] + red[5] + red[6] + red[7];
    float mu  = S * (1.0f / 512.0f);
    float var = Q * (1.0f / 512.0f) - mu * mu;
    float r = rsqrtf(var + 1e-5f);
    Y[base + t]       = f2bf((x0 - mu) * r * g[t] + b[t]);
    Y[base + t + 256] = f2bf((x1 - mu) * r * g[t + 256] + b[t + 256]);
}

// ---------------- weight transpose + bf16 cast: W (K x N) -> WT (N x K) ----------------
__global__ void transpose_bf16(const float* __restrict__ W, unsigned short* __restrict__ WT,
                               int K, int N) {
    __shared__ float t[32][33];
    const int n0 = blockIdx.x * 32, k0 = blockIdx.y * 32;
    const int tx = threadIdx.x & 31, ty = threadIdx.x >> 5;
    #pragma unroll
    for (int r = 0; r < 32; r += 8)
        t[ty + r][tx] = W[(size_t)(k0 + ty + r) * N + n0 + tx];
    __syncthreads();
    #pragma unroll
    for (int r = 0; r < 32; r += 8)
        WT[(size_t)(n0 + ty + r) * K + k0 + tx] = f2bf(t[tx][ty + r]);
}

// ---------------- bf16 MFMA GEMM ----------------
// A: M x K bf16 row-major; BT: N x K bf16 row-major. 128x128 tile, BK=64.
// OM: 0 = f32 out, 1 = bf16 out, 2 = qkv split (Q,K -> Cv stride 1024; V -> vTout transposed)
template <int ACT, int RES, int OM>
__global__ __launch_bounds__(256)
void gemm_mfma(const unsigned short* __restrict__ A, const unsigned short* __restrict__ BT,
               const float* __restrict__ bias, const float* __restrict__ res,
               void* __restrict__ Cv, unsigned short* __restrict__ vTout,
               int M, int N, int K) {
    __shared__ unsigned short As[128 * 64];
    __shared__ unsigned short Bs[128 * 64];
    const int tid = threadIdx.x;
    const int wave = tid >> 6, lane = tid & 63;
    const int wm = (wave >> 1) * 64, wn = (wave & 1) * 64;
    const int bm = blockIdx.y * 128, bn = blockIdx.x * 128;

    f32x4 acc[4][4] = {};

    for (int k0 = 0; k0 < K; k0 += 64) {
        __syncthreads();
        #pragma unroll
        for (int it = 0; it < 4; ++it) {
            const int s = it * 256 + tid;
            const int row = s >> 3, pch = s & 7;
            const int lch = pch ^ (row & 7);
            const unsigned short* ga = A + (size_t)(bm + row) * K + k0 + lch * 8;
            __builtin_amdgcn_global_load_lds(
                (const __attribute__((address_space(1))) void*)ga,
                (__attribute__((address_space(3))) void*)(As + s * 8), 16, 0, 0);
            const unsigned short* gb = BT + (size_t)(bn + row) * K + k0 + lch * 8;
            __builtin_amdgcn_global_load_lds(
                (const __attribute__((address_space(1))) void*)gb,
                (__attribute__((address_space(3))) void*)(Bs + s * 8), 16, 0, 0);
        }
        __syncthreads();
        #pragma unroll
        for (int ks = 0; ks < 2; ++ks) {
            bf16x8 af[4], bfr[4];
            #pragma unroll
            for (int i = 0; i < 4; ++i) {
                const int row = wm + i * 16 + (lane & 15);
                const int pch = (ks * 4 + (lane >> 4)) ^ (row & 7);
                af[i] = *(const bf16x8*)(As + row * 64 + pch * 8);
            }
            #pragma unroll
            for (int j = 0; j < 4; ++j) {
                const int row = wn + j * 16 + (lane & 15);
                const int pch = (ks * 4 + (lane >> 4)) ^ (row & 7);
                bfr[j] = *(const bf16x8*)(Bs + row * 64 + pch * 8);
            }
            #pragma unroll
            for (int i = 0; i < 4; ++i)
                #pragma unroll
                for (int j = 0; j < 4; ++j)
                    acc[i][j] = __builtin_amdgcn_mfma_f32_16x16x32_bf16(
                        af[i], bfr[j], acc[i][j], 0, 0, 0);
        }
    }

    const int cl = lane & 15, rq = (lane >> 4) * 4;
    #pragma unroll
    for (int j = 0; j < 4; ++j) {
        const int col = bn + wn + j * 16 + cl;
        const float bv = bias[col];
        #pragma unroll
        for (int i = 0; i < 4; ++i) {
            const int r0 = bm + wm + i * 16 + rq;
            #pragma unroll
            for (int r = 0; r < 4; ++r) {
                float v = acc[i][j][r] + bv;
                if (ACT == 1) v = 0.5f * v * (1.0f + erff(v * 0.70710678118654752f));
                if (RES) v += res[(size_t)(r0 + r) * N + col];
                if (OM == 0) {
                    ((float*)Cv)[(size_t)(r0 + r) * N + col] = v;
                } else if (OM == 1) {
                    ((unsigned short*)Cv)[(size_t)(r0 + r) * N + col] = f2bf(v);
                } else {
                    const int row = r0 + r;
                    if (col < 1024) {
                        ((unsigned short*)Cv)[(size_t)row * 1024 + col] = f2bf(v);
                    } else {
                        const int hh = (col - 1024) >> 6, dd = (col - 1024) & 63;
                        vTout[(size_t)((((row >> 9) * NH + hh) << 6) + dd) * 512 + (row & 511)] = f2bf(v);
                    }
                }
            }
        }
    }
}

// ---------------- fused flash attention, all heads per block ----------------
// grid: (qg=32, b=32), 512 threads = 8 waves; wave w = head w, all waves share
// the same 16 q rows -> inter float4 reads are identical across waves (L1/L2
// served, each inter element fetched from HBM by exactly ONE block).
// qk: [B*512][1024] bf16  (cols 0..511 = Q(h*64+d), 512..1023 = K(h*64+d))
// vT: [B*NH][64][512] bf16  (V transposed: [d][kpos])
// O : [B*512][512] bf16
__global__ __launch_bounds__(512)
void flash_kernel(const unsigned short* __restrict__ qk,
                  const unsigned short* __restrict__ vT,
                  const float* __restrict__ inter,
                  const float* __restrict__ iw,
                  unsigned short* __restrict__ O) {
    __shared__ unsigned short plds[8][16 * 72];  // per-wave P tile, stride 72
    const int qg = blockIdx.x, b = blockIdx.y;
    const int tid = threadIdx.x, wave = tid >> 6, lane = tid & 63;
    const int h = wave;
    const int lo = lane & 15, hi = lane >> 4;
    const int qA  = qg * 16 + lo;        // A-frag row (q)
    const int qC0 = qg * 16 + hi * 4;    // C-layout row base (+reg)

    const float iw0 = iw[h], iw1 = iw[8 + h], iw2 = iw[16 + h], iw3 = iw[24 + h];

    // Q fragments (fixed for whole block)
    const unsigned short* qp = qk + ((size_t)(b * 512 + qA)) * 1024 + h * 64 + hi * 8;
    const bf16x8 qf0 = *(const bf16x8*)(qp);
    const bf16x8 qf1 = *(const bf16x8*)(qp + 32);

    f32x4 o[4] = {};
    float m[4] = {-1e30f, -1e30f, -1e30f, -1e30f};
    float lsum[4] = {};

    const float* interb = inter + (size_t)b * 512 * 512 * 4;
    const unsigned short* vbase = vT + ((size_t)(b * NH + h)) * 64 * 512;
    unsigned short* pw = &plds[wave][0];

    for (int kt = 0; kt < 8; ++kt) {
        const int kb = kt * 64;
        // ---- S = Q K^T ----
        f32x4 s[4] = {};
        const unsigned short* kp = qk + ((size_t)(b * 512 + kb)) * 1024 + 512 + h * 64 + hi * 8;
        #pragma unroll
        for (int kk = 0; kk < 2; ++kk) {
            const bf16x8 qf = kk ? qf1 : qf0;
            #pragma unroll
            for (int j = 0; j < 4; ++j) {
                bf16x8 kf = *(const bf16x8*)(kp + (size_t)(j * 16 + lo) * 1024 + kk * 32);
                s[j] = __builtin_amdgcn_mfma_f32_16x16x32_bf16(qf, kf, s[j], 0, 0, 0);
            }
        }
        // ---- bias + scale (inter reads identical across the 8 waves) ----
        float sv[4][4];
        #pragma unroll
        for (int j = 0; j < 4; ++j) {
            const int kpos = kb + j * 16 + lo;
            #pragma unroll
            for (int r = 0; r < 4; ++r) {
                const float4 f = *(const float4*)(interb + ((size_t)(qC0 + r) * 512 + kpos) * 4);
                sv[j][r] = s[j][r] * 0.125f + f.x * iw0 + f.y * iw1 + f.z * iw2 + f.w * iw3;
            }
        }
        // ---- online softmax ----
        float alpha[4];
        #pragma unroll
        for (int r = 0; r < 4; ++r) {
            float t = fmaxf(fmaxf(sv[0][r], sv[1][r]), fmaxf(sv[2][r], sv[3][r]));
            #pragma unroll
            for (int off = 1; off < 16; off <<= 1) t = fmaxf(t, __shfl_xor(t, off));
            const float mn = fmaxf(m[r], t);
            alpha[r] = __expf(m[r] - mn);
            m[r] = mn;
        }
        float p[4][4];
        #pragma unroll
        for (int j = 0; j < 4; ++j)
            #pragma unroll
            for (int r = 0; r < 4; ++r)
                p[j][r] = __expf(sv[j][r] - m[r]);
        #pragma unroll
        for (int r = 0; r < 4; ++r) {
            float t = p[0][r] + p[1][r] + p[2][r] + p[3][r];
            #pragma unroll
            for (int off = 1; off < 16; off <<= 1) t += __shfl_xor(t, off);
            lsum[r] = lsum[r] * alpha[r] + t;
        }
        #pragma unroll
        for (int j2 = 0; j2 < 4; ++j2) {
            o[j2][0] *= alpha[0]; o[j2][1] *= alpha[1];
            o[j2][2] *= alpha[2]; o[j2][3] *= alpha[3];
        }
        // ---- P: C-layout -> LDS -> A-layout (wave-private, no barrier) ----
        #pragma unroll
        for (int j = 0; j < 4; ++j)
            #pragma unroll
            for (int r = 0; r < 4; ++r)
                pw[(hi * 4 + r) * 72 + j * 16 + lo] = f2bf(p[j][r]);
        // ---- O += P V ----
        #pragma unroll
        for (int kk = 0; kk < 2; ++kk) {
            const bf16x8 pf = *(const bf16x8*)(pw + lo * 72 + kk * 32 + hi * 8);
            #pragma unroll
            for (int j2 = 0; j2 < 4; ++j2) {
                bf16x8 vf = *(const bf16x8*)(vbase + (size_t)(j2 * 16 + lo) * 512 + kb + kk * 32 + hi * 8);
                o[j2] = __builtin_amdgcn_mfma_f32_16x16x32_bf16(pf, vf, o[j2], 0, 0, 0);
            }
        }
    }
    // ---- epilogue ----
    float inv[4];
    #pragma unroll
    for (int r = 0; r < 4; ++r) inv[r] = 1.0f / lsum[r];
    #pragma unroll
    for (int j2 = 0; j2 < 4; ++j2)
        #pragma unroll
        for (int r = 0; r < 4; ++r)
            O[(size_t)(b * 512 + qC0 + r) * 512 + h * 64 + j2 * 16 + lo] = f2bf(o[j2][r] * inv[r]);
}

// ---------------- launch ----------------
extern "C" void kernel_launch(void* const* d_in, const int* in_sizes, int n_in,
                              void* d_out, int out_size, void* d_ws, size_t ws_size,
                              hipStream_t stream) {
    const float* x     = (const float*)d_in[0];
    const float* inter = (const float*)d_in[1];
    const float* qkv_w = (const float*)d_in[2];
    const float* qkv_b = (const float*)d_in[3];
    const float* out_w = (const float*)d_in[4];
    const float* out_b = (const float*)d_in[5];
    const float* n1g   = (const float*)d_in[6];
    const float* n1b   = (const float*)d_in[7];
    const float* n2g   = (const float*)d_in[8];
    const float* n2b   = (const float*)d_in[9];
    const float* iw    = (const float*)d_in[10];
    const float* fw1   = (const float*)d_in[11];
    const float* fb1   = (const float*)d_in[12];
    const float* fw2   = (const float*)d_in[13];
    const float* fb2   = (const float*)d_in[14];
    float* out = (float*)d_out;

    // workspace layout (bytes): total 190,840,832
    if (ws_size < 190840832ull) return;
    char* ws = (char*)d_ws;
    unsigned short* qk_bf   = (unsigned short*)(ws);
    unsigned short* vT      = (unsigned short*)(ws + 33554432ull);
    unsigned short* attnout = (unsigned short*)(ws + 50331648ull);
    float*          x2      = (float*)(ws + 67108864ull);
    unsigned short* h_bf    = (unsigned short*)(ws + 100663296ull);
    unsigned short* ffnmid  = (unsigned short*)(ws + 117440512ull);
    unsigned short* qkv_wT  = (unsigned short*)(ws + 184549376ull);
    unsigned short* out_wT  = (unsigned short*)(ws + 186122240ull);
    unsigned short* fw1T    = (unsigned short*)(ws + 186646528ull);
    unsigned short* fw2T    = (unsigned short*)(ws + 188743680ull);

    const int M = BB * LL;  // 16384

    // 0. weight transposes -> bf16 B^T
    transpose_bf16<<<dim3(1536 / 32, 512 / 32), 256, 0, stream>>>(qkv_w, qkv_wT, 512, 1536);
    transpose_bf16<<<dim3(512 / 32, 512 / 32), 256, 0, stream>>>(out_w, out_wT, 512, 512);
    transpose_bf16<<<dim3(2048 / 32, 512 / 32), 256, 0, stream>>>(fw1, fw1T, 512, 2048);
    transpose_bf16<<<dim3(512 / 32, 2048 / 32), 256, 0, stream>>>(fw2, fw2T, 2048, 512);
    // 1. LN1: x -> h_bf
    ln_kernel<<<M, 256, 0, stream>>>(x, n1g, n1b, h_bf);
    // 2. qkv GEMM -> qk_bf (Q,K) + vT (V transposed)
    gemm_mfma<0, 0, 2><<<dim3(1536 / 128, M / 128), 256, 0, stream>>>(
        h_bf, qkv_wT, qkv_b, nullptr, qk_bf, vT, M, 1536, 512);
    // 3. fused flash attention (all 8 heads per block; inter read once from HBM)
    flash_kernel<<<dim3(LL / 16, BB), 512, 0, stream>>>(qk_bf, vT, inter, iw, attnout);
    // 4. x2 = x + attnout @ out_w + out_b
    gemm_mfma<0, 1, 0><<<dim3(512 / 128, M / 128), 256, 0, stream>>>(
        attnout, out_wT, out_b, x, x2, nullptr, M, 512, 512);
    // 5. LN2: x2 -> h_bf
    ln_kernel<<<M, 256, 0, stream>>>(x2, n2g, n2b, h_bf);
    // 6. ffnmid = gelu(h2 @ fw1 + fb1) -> bf16
    gemm_mfma<1, 0, 1><<<dim3(2048 / 128, M / 128), 256, 0, stream>>>(
        h_bf, fw1T, fb1, nullptr, ffnmid, nullptr, M, 2048, 512);
    // 7. out = x2 + ffnmid @ fw2 + fb2
    gemm_mfma<0, 1, 0><<<dim3(512 / 128, M / 128), 256, 0, stream>>>(
        ffnmid, fw2T, fb2, x2, out, nullptr, M, 512, 2048);
}

// Round 5
// 620.501 us; speedup vs baseline: 3.4523x; 1.1604x over previous
//
#include <hip/hip_runtime.h>
#include <math.h>

#define BB 32
#define LL 512
#define DD 512
#define NH 8
#define HD 64

typedef __attribute__((ext_vector_type(8))) short bf16x8;
typedef __attribute__((ext_vector_type(4))) float f32x4;

__device__ __forceinline__ unsigned short f2bf(float x) {
    union { float f; unsigned u; } v; v.f = x;
    unsigned r = v.u + 0x7fffu + ((v.u >> 16) & 1u);  // RNE
    return (unsigned short)(r >> 16);
}

// ---------------- reductions ----------------
__device__ __forceinline__ float warp_sum(float v) {
    #pragma unroll
    for (int o = 32; o > 0; o >>= 1) v += __shfl_down(v, o);
    return v;
}

// ---------------- LayerNorm: one block per row of 512, bf16 out ----------------
__global__ void ln_kernel(const float* __restrict__ X, const float* __restrict__ g,
                          const float* __restrict__ b, unsigned short* __restrict__ Y) {
    __shared__ float red[8];
    const size_t base = (size_t)blockIdx.x * DD;
    const int t = threadIdx.x;
    float x0 = X[base + t], x1 = X[base + t + 256];
    float s = warp_sum(x0 + x1);
    float q = warp_sum(x0 * x0 + x1 * x1);
    if ((t & 63) == 0) { red[t >> 6] = s; red[4 + (t >> 6)] = q; }
    __syncthreads();
    float S = red[0] + red[1] + red[2] + red[3];
    float Q = red[4] + red[5] + red[6] + red[7];
    float mu  = S * (1.0f / 512.0f);
    float var = Q * (1.0f / 512.0f) - mu * mu;
    float r = rsqrtf(var + 1e-5f);
    Y[base + t]       = f2bf((x0 - mu) * r * g[t] + b[t]);
    Y[base + t + 256] = f2bf((x1 - mu) * r * g[t + 256] + b[t + 256]);
}

// ---------------- weight transpose + bf16 cast: W (K x N) -> WT (N x K) ----------------
__global__ void transpose_bf16(const float* __restrict__ W, unsigned short* __restrict__ WT,
                               int K, int N) {
    __shared__ float t[32][33];
    const int n0 = blockIdx.x * 32, k0 = blockIdx.y * 32;
    const int tx = threadIdx.x & 31, ty = threadIdx.x >> 5;
    #pragma unroll
    for (int r = 0; r < 32; r += 8)
        t[ty + r][tx] = W[(size_t)(k0 + ty + r) * N + n0 + tx];
    __syncthreads();
    #pragma unroll
    for (int r = 0; r < 32; r += 8)
        WT[(size_t)(n0 + ty + r) * K + k0 + tx] = f2bf(t[tx][ty + r]);
}

// ---------------- bf16 MFMA GEMM ----------------
// A: M x K bf16 row-major; BT: N x K bf16 row-major. 128x128 tile, BK=64.
// OM: 0 = f32 out, 1 = bf16 out, 2 = qkv split (Q,K -> Cv stride 1024; V -> vTout transposed)
template <int ACT, int RES, int OM>
__global__ __launch_bounds__(256)
void gemm_mfma(const unsigned short* __restrict__ A, const unsigned short* __restrict__ BT,
               const float* __restrict__ bias, const float* __restrict__ res,
               void* __restrict__ Cv, unsigned short* __restrict__ vTout,
               int M, int N, int K) {
    __shared__ unsigned short As[128 * 64];
    __shared__ unsigned short Bs[128 * 64];
    const int tid = threadIdx.x;
    const int wave = tid >> 6, lane = tid & 63;
    const int wm = (wave >> 1) * 64, wn = (wave & 1) * 64;
    const int bm = blockIdx.y * 128, bn = blockIdx.x * 128;

    f32x4 acc[4][4] = {};

    for (int k0 = 0; k0 < K; k0 += 64) {
        __syncthreads();
        #pragma unroll
        for (int it = 0; it < 4; ++it) {
            const int s = it * 256 + tid;
            const int row = s >> 3, pch = s & 7;
            const int lch = pch ^ (row & 7);
            const unsigned short* ga = A + (size_t)(bm + row) * K + k0 + lch * 8;
            __builtin_amdgcn_global_load_lds(
                (const __attribute__((address_space(1))) void*)ga,
                (__attribute__((address_space(3))) void*)(As + s * 8), 16, 0, 0);
            const unsigned short* gb = BT + (size_t)(bn + row) * K + k0 + lch * 8;
            __builtin_amdgcn_global_load_lds(
                (const __attribute__((address_space(1))) void*)gb,
                (__attribute__((address_space(3))) void*)(Bs + s * 8), 16, 0, 0);
        }
        __syncthreads();
        #pragma unroll
        for (int ks = 0; ks < 2; ++ks) {
            bf16x8 af[4], bfr[4];
            #pragma unroll
            for (int i = 0; i < 4; ++i) {
                const int row = wm + i * 16 + (lane & 15);
                const int pch = (ks * 4 + (lane >> 4)) ^ (row & 7);
                af[i] = *(const bf16x8*)(As + row * 64 + pch * 8);
            }
            #pragma unroll
            for (int j = 0; j < 4; ++j) {
                const int row = wn + j * 16 + (lane & 15);
                const int pch = (ks * 4 + (lane >> 4)) ^ (row & 7);
                bfr[j] = *(const bf16x8*)(Bs + row * 64 + pch * 8);
            }
            #pragma unroll
            for (int i = 0; i < 4; ++i)
                #pragma unroll
                for (int j = 0; j < 4; ++j)
                    acc[i][j] = __builtin_amdgcn_mfma_f32_16x16x32_bf16(
                        af[i], bfr[j], acc[i][j], 0, 0, 0);
        }
    }

    const int cl = lane & 15, rq = (lane >> 4) * 4;
    #pragma unroll
    for (int j = 0; j < 4; ++j) {
        const int col = bn + wn + j * 16 + cl;
        const float bv = bias[col];
        #pragma unroll
        for (int i = 0; i < 4; ++i) {
            const int r0 = bm + wm + i * 16 + rq;
            #pragma unroll
            for (int r = 0; r < 4; ++r) {
                float v = acc[i][j][r] + bv;
                if (ACT == 1) v = 0.5f * v * (1.0f + erff(v * 0.70710678118654752f));
                if (RES) v += res[(size_t)(r0 + r) * N + col];
                if (OM == 0) {
                    ((float*)Cv)[(size_t)(r0 + r) * N + col] = v;
                } else if (OM == 1) {
                    ((unsigned short*)Cv)[(size_t)(r0 + r) * N + col] = f2bf(v);
                } else {
                    const int row = r0 + r;
                    if (col < 1024) {
                        ((unsigned short*)Cv)[(size_t)row * 1024 + col] = f2bf(v);
                    } else {
                        const int hh = (col - 1024) >> 6, dd = (col - 1024) & 63;
                        vTout[(size_t)((((row >> 9) * NH + hh) << 6) + dd) * 512 + (row & 511)] = f2bf(v);
                    }
                }
            }
        }
    }
}

// ---------------- fused flash attention, all heads per block ----------------
// grid: (qg=32, b=32), 512 threads = 8 waves; wave w = head w.
// inter tile (16 q rows x 64 k x 4 feats = 16 KB) is staged into LDS via
// async global_load_lds, double-buffered: tile kt+1 is issued right after the
// barrier and lands while tile kt is being consumed (ds_read_b128).
__global__ __launch_bounds__(512)
void flash_kernel(const unsigned short* __restrict__ qk,
                  const unsigned short* __restrict__ vT,
                  const float* __restrict__ inter,
                  const float* __restrict__ iw,
                  unsigned short* __restrict__ O) {
    __shared__ float itile[2][16 * 256];         // 2 x 16 KB inter tiles
    __shared__ unsigned short plds[8][16 * 72];  // per-wave P tile
    const int qg = blockIdx.x, b = blockIdx.y;
    const int tid = threadIdx.x, wave = tid >> 6, lane = tid & 63;
    const int h = wave;
    const int lo = lane & 15, hi = lane >> 4;
    const int qA  = qg * 16 + lo;        // A-frag row (q)
    const int qC0 = qg * 16 + hi * 4;    // C-layout row base (+reg)

    const float iw0 = iw[h], iw1 = iw[8 + h], iw2 = iw[16 + h], iw3 = iw[24 + h];

    const float* interb = inter + (size_t)b * 512 * 512 * 4;
    const unsigned short* vbase = vT + ((size_t)(b * NH + h)) * 64 * 512;
    unsigned short* pw = &plds[wave][0];

    // Q fragments (fixed for whole block)
    const unsigned short* qp = qk + ((size_t)(b * 512 + qA)) * 1024 + h * 64 + hi * 8;
    const bf16x8 qf0 = *(const bf16x8*)(qp);
    const bf16x8 qf1 = *(const bf16x8*)(qp + 32);

    f32x4 o[4] = {};
    float m[4] = {-1e30f, -1e30f, -1e30f, -1e30f};
    float lsum[4] = {};

    // stage tile 0: wave w stages q-rows {2w, 2w+1}; lane-linear 16B chunks
    #pragma unroll
    for (int i = 0; i < 2; ++i) {
        const int row = wave * 2 + i;
        const float* src = interb + ((size_t)(qg * 16 + row) * 512 + 0) * 4 + lane * 4;
        __builtin_amdgcn_global_load_lds(
            (const __attribute__((address_space(1))) void*)src,
            (__attribute__((address_space(3))) void*)(&itile[0][row * 256] + lane * 4),
            16, 0, 0);
    }

    for (int kt = 0; kt < 8; ++kt) {
        const int kb = kt * 64;
        const int buf = kt & 1;
        __syncthreads();  // drains vmcnt: tile kt landed; prev compute done with buf^1
        if (kt < 7) {     // prefetch tile kt+1 into the other buffer (async)
            #pragma unroll
            for (int i = 0; i < 2; ++i) {
                const int row = wave * 2 + i;
                const float* src = interb + ((size_t)(qg * 16 + row) * 512 + kb + 64) * 4 + lane * 4;
                __builtin_amdgcn_global_load_lds(
                    (const __attribute__((address_space(1))) void*)src,
                    (__attribute__((address_space(3))) void*)(&itile[buf ^ 1][row * 256] + lane * 4),
                    16, 0, 0);
            }
        }
        // ---- S = Q K^T ----
        f32x4 s[4] = {};
        const unsigned short* kp = qk + ((size_t)(b * 512 + kb)) * 1024 + 512 + h * 64 + hi * 8;
        #pragma unroll
        for (int kk = 0; kk < 2; ++kk) {
            const bf16x8 qf = kk ? qf1 : qf0;
            #pragma unroll
            for (int j = 0; j < 4; ++j) {
                bf16x8 kf = *(const bf16x8*)(kp + (size_t)(j * 16 + lo) * 1024 + kk * 32);
                s[j] = __builtin_amdgcn_mfma_f32_16x16x32_bf16(qf, kf, s[j], 0, 0, 0);
            }
        }
        // ---- bias + scale from LDS tile ----
        float sv[4][4];
        #pragma unroll
        for (int j = 0; j < 4; ++j) {
            #pragma unroll
            for (int r = 0; r < 4; ++r) {
                const float4 f = *(const float4*)&itile[buf][(hi * 4 + r) * 256 + (j * 16 + lo) * 4];
                sv[j][r] = s[j][r] * 0.125f + f.x * iw0 + f.y * iw1 + f.z * iw2 + f.w * iw3;
            }
        }
        // ---- online softmax ----
        float alpha[4];
        #pragma unroll
        for (int r = 0; r < 4; ++r) {
            float t = fmaxf(fmaxf(sv[0][r], sv[1][r]), fmaxf(sv[2][r], sv[3][r]));
            #pragma unroll
            for (int off = 1; off < 16; off <<= 1) t = fmaxf(t, __shfl_xor(t, off));
            const float mn = fmaxf(m[r], t);
            alpha[r] = __expf(m[r] - mn);
            m[r] = mn;
        }
        float p[4][4];
        #pragma unroll
        for (int j = 0; j < 4; ++j)
            #pragma unroll
            for (int r = 0; r < 4; ++r)
                p[j][r] = __expf(sv[j][r] - m[r]);
        #pragma unroll
        for (int r = 0; r < 4; ++r) {
            float t = p[0][r] + p[1][r] + p[2][r] + p[3][r];
            #pragma unroll
            for (int off = 1; off < 16; off <<= 1) t += __shfl_xor(t, off);
            lsum[r] = lsum[r] * alpha[r] + t;
        }
        #pragma unroll
        for (int j2 = 0; j2 < 4; ++j2) {
            o[j2][0] *= alpha[0]; o[j2][1] *= alpha[1];
            o[j2][2] *= alpha[2]; o[j2][3] *= alpha[3];
        }
        // ---- P: C-layout -> LDS -> A-layout (wave-private, no barrier) ----
        #pragma unroll
        for (int j = 0; j < 4; ++j)
            #pragma unroll
            for (int r = 0; r < 4; ++r)
                pw[(hi * 4 + r) * 72 + j * 16 + lo] = f2bf(p[j][r]);
        // ---- O += P V ----
        #pragma unroll
        for (int kk = 0; kk < 2; ++kk) {
            const bf16x8 pf = *(const bf16x8*)(pw + lo * 72 + kk * 32 + hi * 8);
            #pragma unroll
            for (int j2 = 0; j2 < 4; ++j2) {
                bf16x8 vf = *(const bf16x8*)(vbase + (size_t)(j2 * 16 + lo) * 512 + kb + kk * 32 + hi * 8);
                o[j2] = __builtin_amdgcn_mfma_f32_16x16x32_bf16(pf, vf, o[j2], 0, 0, 0);
            }
        }
    }
    // ---- epilogue ----
    float inv[4];
    #pragma unroll
    for (int r = 0; r < 4; ++r) inv[r] = 1.0f / lsum[r];
    #pragma unroll
    for (int j2 = 0; j2 < 4; ++j2)
        #pragma unroll
        for (int r = 0; r < 4; ++r)
            O[(size_t)(b * 512 + qC0 + r) * 512 + h * 64 + j2 * 16 + lo] = f2bf(o[j2][r] * inv[r]);
}

// ---------------- launch ----------------
extern "C" void kernel_launch(void* const* d_in, const int* in_sizes, int n_in,
                              void* d_out, int out_size, void* d_ws, size_t ws_size,
                              hipStream_t stream) {
    const float* x     = (const float*)d_in[0];
    const float* inter = (const float*)d_in[1];
    const float* qkv_w = (const float*)d_in[2];
    const float* qkv_b = (const float*)d_in[3];
    const float* out_w = (const float*)d_in[4];
    const float* out_b = (const float*)d_in[5];
    const float* n1g   = (const float*)d_in[6];
    const float* n1b   = (const float*)d_in[7];
    const float* n2g   = (const float*)d_in[8];
    const float* n2b   = (const float*)d_in[9];
    const float* iw    = (const float*)d_in[10];
    const float* fw1   = (const float*)d_in[11];
    const float* fb1   = (const float*)d_in[12];
    const float* fw2   = (const float*)d_in[13];
    const float* fb2   = (const float*)d_in[14];
    float* out = (float*)d_out;

    // workspace layout (bytes): total 190,840,832
    if (ws_size < 190840832ull) return;
    char* ws = (char*)d_ws;
    unsigned short* qk_bf   = (unsigned short*)(ws);
    unsigned short* vT      = (unsigned short*)(ws + 33554432ull);
    unsigned short* attnout = (unsigned short*)(ws + 50331648ull);
    float*          x2      = (float*)(ws + 67108864ull);
    unsigned short* h_bf    = (unsigned short*)(ws + 100663296ull);
    unsigned short* ffnmid  = (unsigned short*)(ws + 117440512ull);
    unsigned short* qkv_wT  = (unsigned short*)(ws + 184549376ull);
    unsigned short* out_wT  = (unsigned short*)(ws + 186122240ull);
    unsigned short* fw1T    = (unsigned short*)(ws + 186646528ull);
    unsigned short* fw2T    = (unsigned short*)(ws + 188743680ull);

    const int M = BB * LL;  // 16384

    // 0. weight transposes -> bf16 B^T
    transpose_bf16<<<dim3(1536 / 32, 512 / 32), 256, 0, stream>>>(qkv_w, qkv_wT, 512, 1536);
    transpose_bf16<<<dim3(512 / 32, 512 / 32), 256, 0, stream>>>(out_w, out_wT, 512, 512);
    transpose_bf16<<<dim3(2048 / 32, 512 / 32), 256, 0, stream>>>(fw1, fw1T, 512, 2048);
    transpose_bf16<<<dim3(512 / 32, 2048 / 32), 256, 0, stream>>>(fw2, fw2T, 2048, 512);
    // 1. LN1: x -> h_bf
    ln_kernel<<<M, 256, 0, stream>>>(x, n1g, n1b, h_bf);
    // 2. qkv GEMM -> qk_bf (Q,K) + vT (V transposed)
    gemm_mfma<0, 0, 2><<<dim3(1536 / 128, M / 128), 256, 0, stream>>>(
        h_bf, qkv_wT, qkv_b, nullptr, qk_bf, vT, M, 1536, 512);
    // 3. fused flash attention (all 8 heads per block; inter staged async via LDS)
    flash_kernel<<<dim3(LL / 16, BB), 512, 0, stream>>>(qk_bf, vT, inter, iw, attnout);
    // 4. x2 = x + attnout @ out_w + out_b
    gemm_mfma<0, 1, 0><<<dim3(512 / 128, M / 128), 256, 0, stream>>>(
        attnout, out_wT, out_b, x, x2, nullptr, M, 512, 512);
    // 5. LN2: x2 -> h_bf
    ln_kernel<<<M, 256, 0, stream>>>(x2, n2g, n2b, h_bf);
    // 6. ffnmid = gelu(h2 @ fw1 + fb1) -> bf16
    gemm_mfma<1, 0, 1><<<dim3(2048 / 128, M / 128), 256, 0, stream>>>(
        h_bf, fw1T, fb1, nullptr, ffnmid, nullptr, M, 2048, 512);
    // 7. out = x2 + ffnmid @ fw2 + fb2
    gemm_mfma<0, 1, 0><<<dim3(512 / 128, M / 128), 256, 0, stream>>>(
        ffnmid, fw2T, fb2, x2, out, nullptr, M, 512, 2048);
}

// Round 6
// 571.918 us; speedup vs baseline: 3.7456x; 1.0849x over previous
//
#include <hip/hip_runtime.h>
#include <math.h>

#define BB 32
#define LL 512
#define DD 512
#define NH 8
#define HD 64

typedef __attribute__((ext_vector_type(8))) short bf16x8;
typedef __attribute__((ext_vector_type(4))) float f32x4;

__device__ __forceinline__ unsigned short f2bf(float x) {
    union { float f; unsigned u; } v; v.f = x;
    unsigned r = v.u + 0x7fffu + ((v.u >> 16) & 1u);  // RNE
    return (unsigned short)(r >> 16);
}

// ---------------- reductions ----------------
__device__ __forceinline__ float warp_sum(float v) {
    #pragma unroll
    for (int o = 32; o > 0; o >>= 1) v += __shfl_down(v, o);
    return v;
}

// ---------------- LayerNorm: one block per row of 512, bf16 out ----------------
__global__ void ln_kernel(const float* __restrict__ X, const float* __restrict__ g,
                          const float* __restrict__ b, unsigned short* __restrict__ Y) {
    __shared__ float red[8];
    const size_t base = (size_t)blockIdx.x * DD;
    const int t = threadIdx.x;
    float x0 = X[base + t], x1 = X[base + t + 256];
    float s = warp_sum(x0 + x1);
    float q = warp_sum(x0 * x0 + x1 * x1);
    if ((t & 63) == 0) { red[t >> 6] = s; red[4 + (t >> 6)] = q; }
    __syncthreads();
    float S = red[0] + red[1] + red[2] + red[3];
    float Q = red[4] + red[5] + red[6] + red[7];
    float mu  = S * (1.0f / 512.0f);
    float var = Q * (1.0f / 512.0f) - mu * mu;
    float r = rsqrtf(var + 1e-5f);
    Y[base + t]       = f2bf((x0 - mu) * r * g[t] + b[t]);
    Y[base + t + 256] = f2bf((x1 - mu) * r * g[t + 256] + b[t + 256]);
}

// ---------------- weight transpose + bf16 cast: W (K x N) -> WT (N x K) ----------------
__global__ void transpose_bf16(const float* __restrict__ W, unsigned short* __restrict__ WT,
                               int K, int N) {
    __shared__ float t[32][33];
    const int n0 = blockIdx.x * 32, k0 = blockIdx.y * 32;
    const int tx = threadIdx.x & 31, ty = threadIdx.x >> 5;
    #pragma unroll
    for (int r = 0; r < 32; r += 8)
        t[ty + r][tx] = W[(size_t)(k0 + ty + r) * N + n0 + tx];
    __syncthreads();
    #pragma unroll
    for (int r = 0; r < 32; r += 8)
        WT[(size_t)(n0 + ty + r) * K + k0 + tx] = f2bf(t[tx][ty + r]);
}

// ---------------- bf16 MFMA GEMM ----------------
// A: M x K bf16 row-major; BT: N x K bf16 row-major. 128x128 tile, BK=64.
// OM: 0 = f32 out, 1 = bf16 out,
//     2 = qkv split: Q -> Cv row-major [row][512]; K -> kfrag blobs; V -> vfrag blobs.
// Fragment blob layout (1 KB each): idx [b][h][kt][kk][j], element (lane*8 + e)
//   K: lane=hi*16+lo holds K[kpos=kt*64+j*16+lo][d=kk*32+hi*8+e]
//   V: lane=hi*16+lo holds V[d=j*16+lo][kpos=kt*64+kk*32+hi*8+e]
template <int ACT, int RES, int OM>
__global__ __launch_bounds__(256)
void gemm_mfma(const unsigned short* __restrict__ A, const unsigned short* __restrict__ BT,
               const float* __restrict__ bias, const float* __restrict__ res,
               void* __restrict__ Cv, unsigned short* __restrict__ kfrag,
               unsigned short* __restrict__ vfrag, int M, int N, int K) {
    __shared__ unsigned short As[128 * 64];
    __shared__ unsigned short Bs[128 * 64];
    const int tid = threadIdx.x;
    const int wave = tid >> 6, lane = tid & 63;
    const int wm = (wave >> 1) * 64, wn = (wave & 1) * 64;
    const int bm = blockIdx.y * 128, bn = blockIdx.x * 128;

    f32x4 acc[4][4] = {};

    for (int k0 = 0; k0 < K; k0 += 64) {
        __syncthreads();
        #pragma unroll
        for (int it = 0; it < 4; ++it) {
            const int s = it * 256 + tid;
            const int row = s >> 3, pch = s & 7;
            const int lch = pch ^ (row & 7);
            const unsigned short* ga = A + (size_t)(bm + row) * K + k0 + lch * 8;
            __builtin_amdgcn_global_load_lds(
                (const __attribute__((address_space(1))) void*)ga,
                (__attribute__((address_space(3))) void*)(As + s * 8), 16, 0, 0);
            const unsigned short* gb = BT + (size_t)(bn + row) * K + k0 + lch * 8;
            __builtin_amdgcn_global_load_lds(
                (const __attribute__((address_space(1))) void*)gb,
                (__attribute__((address_space(3))) void*)(Bs + s * 8), 16, 0, 0);
        }
        __syncthreads();
        #pragma unroll
        for (int ks = 0; ks < 2; ++ks) {
            bf16x8 af[4], bfr[4];
            #pragma unroll
            for (int i = 0; i < 4; ++i) {
                const int row = wm + i * 16 + (lane & 15);
                const int pch = (ks * 4 + (lane >> 4)) ^ (row & 7);
                af[i] = *(const bf16x8*)(As + row * 64 + pch * 8);
            }
            #pragma unroll
            for (int j = 0; j < 4; ++j) {
                const int row = wn + j * 16 + (lane & 15);
                const int pch = (ks * 4 + (lane >> 4)) ^ (row & 7);
                bfr[j] = *(const bf16x8*)(Bs + row * 64 + pch * 8);
            }
            #pragma unroll
            for (int i = 0; i < 4; ++i)
                #pragma unroll
                for (int j = 0; j < 4; ++j)
                    acc[i][j] = __builtin_amdgcn_mfma_f32_16x16x32_bf16(
                        af[i], bfr[j], acc[i][j], 0, 0, 0);
        }
    }

    const int cl = lane & 15, rq = (lane >> 4) * 4;
    #pragma unroll
    for (int j = 0; j < 4; ++j) {
        const int col = bn + wn + j * 16 + cl;
        const float bv = bias[col];
        #pragma unroll
        for (int i = 0; i < 4; ++i) {
            const int r0 = bm + wm + i * 16 + rq;
            #pragma unroll
            for (int r = 0; r < 4; ++r) {
                float v = acc[i][j][r] + bv;
                if (ACT == 1) v = 0.5f * v * (1.0f + erff(v * 0.70710678118654752f));
                if (RES) v += res[(size_t)(r0 + r) * N + col];
                if (OM == 0) {
                    ((float*)Cv)[(size_t)(r0 + r) * N + col] = v;
                } else if (OM == 1) {
                    ((unsigned short*)Cv)[(size_t)(r0 + r) * N + col] = f2bf(v);
                } else {
                    const int row = r0 + r;
                    const int b = row >> 9, kpos = row & 511;
                    if (col < 512) {
                        ((unsigned short*)Cv)[(size_t)row * 512 + col] = f2bf(v);
                    } else if (col < 1024) {
                        const int h = (col - 512) >> 6, dd = (col - 512) & 63;
                        const int kt = kpos >> 6, jj = (kpos >> 4) & 3, lo2 = kpos & 15;
                        const int kk = dd >> 5, hi2 = (dd >> 3) & 3, e = dd & 7;
                        kfrag[((((size_t)(b * NH + h) * 8 + kt) * 2 + kk) * 4 + jj) * 512
                              + (hi2 * 16 + lo2) * 8 + e] = f2bf(v);
                    } else {
                        const int h = (col - 1024) >> 6, dd = (col - 1024) & 63;
                        const int kt = kpos >> 6, kk = (kpos >> 5) & 1, hi2 = (kpos >> 3) & 3, e = kpos & 7;
                        const int jj = dd >> 4, lo2 = dd & 15;
                        vfrag[((((size_t)(b * NH + h) * 8 + kt) * 2 + kk) * 4 + jj) * 512
                              + (hi2 * 16 + lo2) * 8 + e] = f2bf(v);
                    }
                }
            }
        }
    }
}

// ---------------- fused flash attention, all heads per block ----------------
// grid: (qg=32, b=32), 512 threads = 8 waves; wave w = head w.
// inter tile (16 KB) staged async into LDS, double-buffered.
// K/V read from pre-packed fragment blobs: every bf16x8 load is lane-contiguous 1 KB.
__global__ __launch_bounds__(512)
void flash_kernel(const unsigned short* __restrict__ qbuf,
                  const unsigned short* __restrict__ kfrag,
                  const unsigned short* __restrict__ vfrag,
                  const float* __restrict__ inter,
                  const float* __restrict__ iw,
                  unsigned short* __restrict__ O) {
    __shared__ float itile[2][16 * 256];         // 2 x 16 KB inter tiles
    __shared__ unsigned short plds[8][16 * 72];  // per-wave P tile
    const int qg = blockIdx.x, b = blockIdx.y;
    const int tid = threadIdx.x, wave = tid >> 6, lane = tid & 63;
    const int h = wave;
    const int lo = lane & 15, hi = lane >> 4;
    const int qA  = qg * 16 + lo;        // A-frag row (q)
    const int qC0 = qg * 16 + hi * 4;    // C-layout row base (+reg)

    const float iw0 = iw[h], iw1 = iw[8 + h], iw2 = iw[16 + h], iw3 = iw[24 + h];

    const float* interb = inter + (size_t)b * 512 * 512 * 4;
    unsigned short* pw = &plds[wave][0];

    // Q fragments (fixed for whole block): d = kk*32 + hi*8 + e
    const unsigned short* qp = qbuf + ((size_t)(b * 512 + qA)) * 512 + h * 64 + hi * 8;
    const bf16x8 qf0 = *(const bf16x8*)(qp);
    const bf16x8 qf1 = *(const bf16x8*)(qp + 32);

    f32x4 o[4] = {};
    float m[4] = {-1e30f, -1e30f, -1e30f, -1e30f};
    float lsum[4] = {};

    // stage tile 0: wave w stages q-rows {2w, 2w+1}; lane-linear 16B chunks
    #pragma unroll
    for (int i = 0; i < 2; ++i) {
        const int row = wave * 2 + i;
        const float* src = interb + ((size_t)(qg * 16 + row) * 512 + 0) * 4 + lane * 4;
        __builtin_amdgcn_global_load_lds(
            (const __attribute__((address_space(1))) void*)src,
            (__attribute__((address_space(3))) void*)(&itile[0][row * 256] + lane * 4),
            16, 0, 0);
    }

    for (int kt = 0; kt < 8; ++kt) {
        const int kb = kt * 64;
        const int buf = kt & 1;
        const size_t fb = (((size_t)(b * NH + h) * 8 + kt) * 2) * 4 * 512;  // frag blob base
        __syncthreads();
        if (kt < 7) {
            #pragma unroll
            for (int i = 0; i < 2; ++i) {
                const int row = wave * 2 + i;
                const float* src = interb + ((size_t)(qg * 16 + row) * 512 + kb + 64) * 4 + lane * 4;
                __builtin_amdgcn_global_load_lds(
                    (const __attribute__((address_space(1))) void*)src,
                    (__attribute__((address_space(3))) void*)(&itile[buf ^ 1][row * 256] + lane * 4),
                    16, 0, 0);
            }
        }
        // ---- S = Q K^T (fragment blobs: contiguous 1 KB loads) ----
        f32x4 s[4] = {};
        #pragma unroll
        for (int kk = 0; kk < 2; ++kk) {
            const bf16x8 qf = kk ? qf1 : qf0;
            #pragma unroll
            for (int j = 0; j < 4; ++j) {
                bf16x8 kf = *(const bf16x8*)(kfrag + fb + (size_t)(kk * 4 + j) * 512 + lane * 8);
                s[j] = __builtin_amdgcn_mfma_f32_16x16x32_bf16(qf, kf, s[j], 0, 0, 0);
            }
        }
        // ---- bias + scale from LDS tile ----
        float sv[4][4];
        #pragma unroll
        for (int j = 0; j < 4; ++j) {
            #pragma unroll
            for (int r = 0; r < 4; ++r) {
                const float4 f = *(const float4*)&itile[buf][(hi * 4 + r) * 256 + (j * 16 + lo) * 4];
                sv[j][r] = s[j][r] * 0.125f + f.x * iw0 + f.y * iw1 + f.z * iw2 + f.w * iw3;
            }
        }
        // ---- online softmax ----
        float alpha[4];
        #pragma unroll
        for (int r = 0; r < 4; ++r) {
            float t = fmaxf(fmaxf(sv[0][r], sv[1][r]), fmaxf(sv[2][r], sv[3][r]));
            #pragma unroll
            for (int off = 1; off < 16; off <<= 1) t = fmaxf(t, __shfl_xor(t, off));
            const float mn = fmaxf(m[r], t);
            alpha[r] = __expf(m[r] - mn);
            m[r] = mn;
        }
        float p[4][4];
        #pragma unroll
        for (int j = 0; j < 4; ++j)
            #pragma unroll
            for (int r = 0; r < 4; ++r)
                p[j][r] = __expf(sv[j][r] - m[r]);
        #pragma unroll
        for (int r = 0; r < 4; ++r) {
            float t = p[0][r] + p[1][r] + p[2][r] + p[3][r];
            #pragma unroll
            for (int off = 1; off < 16; off <<= 1) t += __shfl_xor(t, off);
            lsum[r] = lsum[r] * alpha[r] + t;
        }
        #pragma unroll
        for (int j2 = 0; j2 < 4; ++j2) {
            o[j2][0] *= alpha[0]; o[j2][1] *= alpha[1];
            o[j2][2] *= alpha[2]; o[j2][3] *= alpha[3];
        }
        // ---- P: C-layout -> LDS -> A-layout (wave-private, no barrier) ----
        #pragma unroll
        for (int j = 0; j < 4; ++j)
            #pragma unroll
            for (int r = 0; r < 4; ++r)
                pw[(hi * 4 + r) * 72 + j * 16 + lo] = f2bf(p[j][r]);
        // ---- O += P V (fragment blobs) ----
        #pragma unroll
        for (int kk = 0; kk < 2; ++kk) {
            const bf16x8 pf = *(const bf16x8*)(pw + lo * 72 + kk * 32 + hi * 8);
            #pragma unroll
            for (int j2 = 0; j2 < 4; ++j2) {
                bf16x8 vf = *(const bf16x8*)(vfrag + fb + (size_t)(kk * 4 + j2) * 512 + lane * 8);
                o[j2] = __builtin_amdgcn_mfma_f32_16x16x32_bf16(pf, vf, o[j2], 0, 0, 0);
            }
        }
    }
    // ---- epilogue ----
    float inv[4];
    #pragma unroll
    for (int r = 0; r < 4; ++r) inv[r] = 1.0f / lsum[r];
    #pragma unroll
    for (int j2 = 0; j2 < 4; ++j2)
        #pragma unroll
        for (int r = 0; r < 4; ++r)
            O[(size_t)(b * 512 + qC0 + r) * 512 + h * 64 + j2 * 16 + lo] = f2bf(o[j2][r] * inv[r]);
}

// ---------------- launch ----------------
extern "C" void kernel_launch(void* const* d_in, const int* in_sizes, int n_in,
                              void* d_out, int out_size, void* d_ws, size_t ws_size,
                              hipStream_t stream) {
    const float* x     = (const float*)d_in[0];
    const float* inter = (const float*)d_in[1];
    const float* qkv_w = (const float*)d_in[2];
    const float* qkv_b = (const float*)d_in[3];
    const float* out_w = (const float*)d_in[4];
    const float* out_b = (const float*)d_in[5];
    const float* n1g   = (const float*)d_in[6];
    const float* n1b   = (const float*)d_in[7];
    const float* n2g   = (const float*)d_in[8];
    const float* n2b   = (const float*)d_in[9];
    const float* iw    = (const float*)d_in[10];
    const float* fw1   = (const float*)d_in[11];
    const float* fb1   = (const float*)d_in[12];
    const float* fw2   = (const float*)d_in[13];
    const float* fb2   = (const float*)d_in[14];
    float* out = (float*)d_out;

    // workspace layout (bytes): total 190,840,832
    //   qbuf    @ 0           : 16,777,216  (16384 x 512 bf16 Q)
    //   kfrag   @ 16777216    : 16,777,216  (fragment blobs)
    //   vfrag   @ 33554432    : 16,777,216  (fragment blobs)
    //   attnout @ 50331648    : 16,777,216
    //   x2      @ 67108864    : 33,554,432  (fp32)
    //   h_bf    @ 100663296   : 16,777,216
    //   ffnmid  @ 117440512   : 67,108,864
    //   weights @ 184549376   : ~6.3 MB
    if (ws_size < 190840832ull) return;
    char* ws = (char*)d_ws;
    unsigned short* qbuf    = (unsigned short*)(ws);
    unsigned short* kfrag   = (unsigned short*)(ws + 16777216ull);
    unsigned short* vfrag   = (unsigned short*)(ws + 33554432ull);
    unsigned short* attnout = (unsigned short*)(ws + 50331648ull);
    float*          x2      = (float*)(ws + 67108864ull);
    unsigned short* h_bf    = (unsigned short*)(ws + 100663296ull);
    unsigned short* ffnmid  = (unsigned short*)(ws + 117440512ull);
    unsigned short* qkv_wT  = (unsigned short*)(ws + 184549376ull);
    unsigned short* out_wT  = (unsigned short*)(ws + 186122240ull);
    unsigned short* fw1T    = (unsigned short*)(ws + 186646528ull);
    unsigned short* fw2T    = (unsigned short*)(ws + 188743680ull);

    const int M = BB * LL;  // 16384

    // 0. weight transposes -> bf16 B^T
    transpose_bf16<<<dim3(1536 / 32, 512 / 32), 256, 0, stream>>>(qkv_w, qkv_wT, 512, 1536);
    transpose_bf16<<<dim3(512 / 32, 512 / 32), 256, 0, stream>>>(out_w, out_wT, 512, 512);
    transpose_bf16<<<dim3(2048 / 32, 512 / 32), 256, 0, stream>>>(fw1, fw1T, 512, 2048);
    transpose_bf16<<<dim3(512 / 32, 2048 / 32), 256, 0, stream>>>(fw2, fw2T, 2048, 512);
    // 1. LN1: x -> h_bf
    ln_kernel<<<M, 256, 0, stream>>>(x, n1g, n1b, h_bf);
    // 2. qkv GEMM -> qbuf + kfrag + vfrag (fragment-packed K/V)
    gemm_mfma<0, 0, 2><<<dim3(1536 / 128, M / 128), 256, 0, stream>>>(
        h_bf, qkv_wT, qkv_b, nullptr, qbuf, kfrag, vfrag, M, 1536, 512);
    // 3. fused flash attention
    flash_kernel<<<dim3(LL / 16, BB), 512, 0, stream>>>(qbuf, kfrag, vfrag, inter, iw, attnout);
    // 4. x2 = x + attnout @ out_w + out_b
    gemm_mfma<0, 1, 0><<<dim3(512 / 128, M / 128), 256, 0, stream>>>(
        attnout, out_wT, out_b, x, x2, nullptr, nullptr, M, 512, 512);
    // 5. LN2: x2 -> h_bf
    ln_kernel<<<M, 256, 0, stream>>>(x2, n2g, n2b, h_bf);
    // 6. ffnmid = gelu(h2 @ fw1 + fb1) -> bf16
    gemm_mfma<1, 0, 1><<<dim3(2048 / 128, M / 128), 256, 0, stream>>>(
        h_bf, fw1T, fb1, nullptr, ffnmid, nullptr, nullptr, M, 2048, 512);
    // 7. out = x2 + ffnmid @ fw2 + fb2
    gemm_mfma<0, 1, 0><<<dim3(512 / 128, M / 128), 256, 0, stream>>>(
        ffnmid, fw2T, fb2, x2, out, nullptr, nullptr, M, 512, 2048);
}